// Round 3
// baseline (790.268 us; speedup 1.0000x reference)
//
#include <hip/hip_runtime.h>
#include <hip/hip_bf16.h>
#include <math.h>

#define PI_F 3.14159265358979323846f

// ---------------------------------------------------------------------------
// Shapes: x (8,64,256,256) f32; weight_fft (64,64,256,129) f32; bias (64) f32
// y (8,64,256,256) f32.
// Workspace: Xf complex packed-bf16 (B=8,C=64,H=256,Wf=129) uint = 270 MB
//   (lo 16 bits = real bf16, hi 16 bits = imag bf16)
// All FFT/einsum arithmetic is fp32; only inter-pass storage is bf16.
//
// Round-3 structure: P2/P3/P4 are independent per w-bin, so they run in two
// w-chunks (w<64, w>=64) whose 135 MB Xf slice stays Infinity-Cache-resident
// across the 3 passes. x/W/y use non-temporal accesses so the streaming
// tensors don't evict Xf from L3.
// ---------------------------------------------------------------------------

__device__ __forceinline__ unsigned brev8(unsigned v) { return __brev(v) >> 24; }

__device__ __forceinline__ unsigned pack_bf(float re, float im) {
    unsigned ur = __float_as_uint(re);
    unsigned ui = __float_as_uint(im);
    ur = (ur + 0x7fffu + ((ur >> 16) & 1u)) >> 16;     // RNE to bf16
    ui = (ui + 0x7fffu + ((ui >> 16) & 1u)) & 0xffff0000u;
    return ur | ui;
}
__device__ __forceinline__ float2 unpack_bf(unsigned p) {
    return make_float2(__uint_as_float(p << 16),
                       __uint_as_float(p & 0xffff0000u));
}

// ---------------- Pass 1: row rfft (256 real -> 129 complex) ----------------
__global__ __launch_bounds__(256) void k_rowfft(const float* __restrict__ x,
                                                unsigned* __restrict__ Xf) {
    __shared__ float2 a[256];
    const int row = blockIdx.x;                 // (b*64+c)*256 + h
    const int t = threadIdx.x;
    const float* xr = x + (size_t)row * 256;
    a[t] = make_float2(__builtin_nontemporal_load(xr + t), 0.0f);
    __syncthreads();
#pragma unroll
    for (int s = 1; s <= 8; ++s) {
        const int half = 1 << (s - 1);
        const int p = t & ~half, q = p | half;
        const int j = t & (half - 1);
        const int rp = (s == 1) ? (int)brev8(p) : p;
        const int rq = (s == 1) ? (int)brev8(q) : q;
        float2 u = a[rp], v = a[rq];
        float sn, cs;
        __sincosf(-PI_F * (float)j / (float)half, &sn, &cs);
        float2 wv = make_float2(cs * v.x - sn * v.y, cs * v.y + sn * v.x);
        const float sig = (t & half) ? -1.0f : 1.0f;
        float2 o = make_float2(u.x + sig * wv.x, u.y + sig * wv.y);
        __syncthreads();
        a[t] = o;
        __syncthreads();
    }
    if (t <= 128) Xf[(size_t)row * 129 + t] = pack_bf(a[t].x, a[t].y);
}

// ------------- Pass 2/4: column FFT along H (in-place, tiled) ---------------
// Block = (b*64+c, w-tile of <=16 columns). LDS a[16][257] (padded).
__global__ __launch_bounds__(256) void k_colfft(unsigned* __restrict__ Xf,
                                                float sgn, int wt0) {
    __shared__ float2 a[16][257];
    const int wt = wt0 + blockIdx.x;
    const int w0 = wt * 16;
    const int TW = min(16, 129 - w0);
    const size_t base = (size_t)blockIdx.y * 256 * 129;
    const int t = threadIdx.x;
    const int wl = t & 15, hb = t >> 4;

#pragma unroll
    for (int it = 0; it < 16; ++it) {
        const int h = it * 16 + hb;
        if (wl < TW) a[wl][h] = unpack_bf(Xf[base + (size_t)h * 129 + w0 + wl]);
    }
    __syncthreads();

#pragma unroll
    for (int s = 1; s <= 8; ++s) {
        const int half = 1 << (s - 1);
        const int p = t & ~half, q = p | half;
        const int j = t & (half - 1);
        const int rp = (s == 1) ? (int)brev8(p) : p;
        const int rq = (s == 1) ? (int)brev8(q) : q;
        float sn, cs;
        __sincosf(sgn * PI_F * (float)j / (float)half, &sn, &cs);
        const float sig = (t & half) ? -1.0f : 1.0f;
        float2 u[16], v[16];
#pragma unroll
        for (int c = 0; c < 16; ++c)
            if (c < TW) { u[c] = a[c][rp]; v[c] = a[c][rq]; }
        __syncthreads();
#pragma unroll
        for (int c = 0; c < 16; ++c)
            if (c < TW) {
                float2 wv = make_float2(cs * v[c].x - sn * v[c].y,
                                        cs * v[c].y + sn * v[c].x);
                a[c][t] = make_float2(u[c].x + sig * wv.x, u[c].y + sig * wv.y);
            }
        __syncthreads();
    }

#pragma unroll
    for (int it = 0; it < 16; ++it) {
        const int h = it * 16 + hb;
        if (wl < TW)
            Xf[base + (size_t)h * 129 + w0 + wl] = pack_bf(a[wl][h].x, a[wl][h].y);
    }
}

// --------------------- Pass 3: per-bin einsum (in-place) --------------------
// Z[b,i,h,w] = sum_o X[b,o,h,w] * W[o,i,h,w]   (W real)
__global__ __launch_bounds__(256) void k_einsum(unsigned* __restrict__ Xf,
                                                const float* __restrict__ Wt,
                                                int wt0, int nwt) {
    __shared__ float2 xs[512][16];              // [(b<<6)|o][wl] = 64 KB fp32
    const int t = threadIdx.x;
    // XCD-chunked swizzle over 256*nwt blocks (divisible by 8).
    const int nb = 256 * nwt;
    const int per = nb >> 3;
    const int bid = blockIdx.x;
    const int nid = (bid & 7) * per + (bid >> 3);
    const int wt = wt0 + nid % nwt;
    const int h = nid / nwt;
    const int w0 = wt * 16;
    const int TW = min(16, 129 - w0);

    // stage X[*, *, h, w0:w0+TW] into LDS (unpack bf16 -> fp32)
#pragma unroll
    for (int k = 0; k < 32; ++k) {
        const int e = t + 256 * k;              // 8192 = 512 pairs * 16 w
        const int pr = e >> 4, wl = e & 15;
        if (wl < TW)
            xs[pr][wl] = unpack_bf(Xf[((size_t)pr * 256 + h) * 129 + w0 + wl]);
    }
    __syncthreads();

    const int wl = t & 15, j = t >> 4;
    float2 acc[4][8];
#pragma unroll
    for (int r = 0; r < 4; ++r)
#pragma unroll
        for (int b = 0; b < 8; ++b) acc[r][b] = make_float2(0.0f, 0.0f);

    if (wl < TW) {
        const float* Wh = Wt + (size_t)h * 129 + w0 + wl;
        for (int o = 0; o < 64; ++o) {
            float2 xv[8];
#pragma unroll
            for (int b = 0; b < 8; ++b) xv[b] = xs[(b << 6) | o][wl];
#pragma unroll
            for (int r = 0; r < 4; ++r) {
                const int i = j + (r << 4);
                const float wv = __builtin_nontemporal_load(
                    Wh + (size_t)((o << 6) | i) * 33024);
#pragma unroll
                for (int b = 0; b < 8; ++b) {
                    acc[r][b].x += xv[b].x * wv;
                    acc[r][b].y += xv[b].y * wv;
                }
            }
        }
    }
    __syncthreads();

    if (wl < TW) {
#pragma unroll
        for (int r = 0; r < 4; ++r) {
            const int i = j + (r << 4);
#pragma unroll
            for (int b = 0; b < 8; ++b) {
                Xf[((size_t)((b << 6) | i) * 256 + h) * 129 + w0 + wl] =
                    pack_bf(acc[r][b].x, acc[r][b].y);
            }
        }
    }
}

// ------------- Pass 5: row irfft (129 complex -> 256 real) + bias -----------
__global__ __launch_bounds__(256) void k_rowifft(const unsigned* __restrict__ Zf,
                                                 const float* __restrict__ bias,
                                                 float* __restrict__ y) {
    __shared__ float2 a[256];
    const int row = blockIdx.x;                 // (b*64+i)*256 + h
    const int ci = (row >> 8) & 63;
    const int t = threadIdx.x;
    const unsigned* zr = Zf + (size_t)row * 129;
    if (t <= 128) {
        float2 v = unpack_bf(zr[t]);
        a[t] = v;
        if (t >= 1 && t <= 127) a[256 - t] = make_float2(v.x, -v.y);
    }
    __syncthreads();
#pragma unroll
    for (int s = 1; s <= 8; ++s) {
        const int half = 1 << (s - 1);
        const int p = t & ~half, q = p | half;
        const int j = t & (half - 1);
        const int rp = (s == 1) ? (int)brev8(p) : p;
        const int rq = (s == 1) ? (int)brev8(q) : q;
        float2 u = a[rp], v = a[rq];
        float sn, cs;
        __sincosf(PI_F * (float)j / (float)half, &sn, &cs);
        float2 wv = make_float2(cs * v.x - sn * v.y, cs * v.y + sn * v.x);
        const float sig = (t & half) ? -1.0f : 1.0f;
        float2 o = make_float2(u.x + sig * wv.x, u.y + sig * wv.y);
        __syncthreads();
        a[t] = o;
        __syncthreads();
    }
    const float b = bias[ci];
    __builtin_nontemporal_store(a[t].x * (1.0f / 65536.0f) + b,
                                y + (size_t)row * 256 + t);
}

// ---------------------------------------------------------------------------
extern "C" void kernel_launch(void* const* d_in, const int* in_sizes, int n_in,
                              void* d_out, int out_size, void* d_ws,
                              size_t ws_size, hipStream_t stream) {
    (void)in_sizes; (void)n_in; (void)out_size; (void)ws_size;
    const float* x    = (const float*)d_in[0];
    const float* wfft = (const float*)d_in[1];
    const float* bias = (const float*)d_in[2];
    float* y = (float*)d_out;
    unsigned* Xf = (unsigned*)d_ws;             // 8*64*256*129 uint = 270 MB

    const int ROWS = 8 * 64 * 256;              // 131072

    k_rowfft<<<ROWS, 256, 0, stream>>>(x, Xf);

    // chunk A: w-tiles 0..3 (w 0..63); chunk B: w-tiles 4..8 (w 64..128)
    k_colfft<<<dim3(4, 512), 256, 0, stream>>>(Xf, -1.0f, 0);
    k_einsum<<<256 * 4, 256, 0, stream>>>(Xf, wfft, 0, 4);
    k_colfft<<<dim3(4, 512), 256, 0, stream>>>(Xf, +1.0f, 0);

    k_colfft<<<dim3(5, 512), 256, 0, stream>>>(Xf, -1.0f, 4);
    k_einsum<<<256 * 5, 256, 0, stream>>>(Xf, wfft, 4, 5);
    k_colfft<<<dim3(5, 512), 256, 0, stream>>>(Xf, +1.0f, 4);

    k_rowifft<<<ROWS, 256, 0, stream>>>(Xf, bias, y);
}

// Round 4
// 553.950 us; speedup vs baseline: 1.4266x; 1.4266x over previous
//
#include <hip/hip_runtime.h>
#include <hip/hip_bf16.h>
#include <math.h>

#define PI_F 3.14159265358979323846f

// ---------------------------------------------------------------------------
// Shapes: x (8,64,256,256) f32; weight_fft (64,64,256,129) f32; bias (64) f32
// y (8,64,256,256) f32.
// Workspace: Xf complex packed-bf16, flat layout [bo][n], n = h*129 + w,
// 512 rows x 33024 bins x 4 B = 270 MB. (lo16 = real bf16, hi16 = imag bf16)
// All FFT/einsum arithmetic fp32; only inter-pass storage is bf16.
//
// Round-4: revert rd3 chunking; einsum retiled to line-aligned flattened-n
// 32-bin tiles (1032 blocks, no tail) so every W/Xf cacheline is fetched once
// and fully used by one block -> NT on W is safe and protects L3 for Xf.
// ---------------------------------------------------------------------------

__device__ __forceinline__ unsigned brev8(unsigned v) { return __brev(v) >> 24; }

__device__ __forceinline__ unsigned pack_bf(float re, float im) {
    unsigned ur = __float_as_uint(re);
    unsigned ui = __float_as_uint(im);
    ur = (ur + 0x7fffu + ((ur >> 16) & 1u)) >> 16;     // RNE to bf16
    ui = (ui + 0x7fffu + ((ui >> 16) & 1u)) & 0xffff0000u;
    return ur | ui;
}
__device__ __forceinline__ float2 unpack_bf(unsigned p) {
    return make_float2(__uint_as_float(p << 16),
                       __uint_as_float(p & 0xffff0000u));
}

// ---------------- Pass 1: row rfft (256 real -> 129 complex) ----------------
__global__ __launch_bounds__(256) void k_rowfft(const float* __restrict__ x,
                                                unsigned* __restrict__ Xf) {
    __shared__ float2 a[256];
    const int row = blockIdx.x;                 // (b*64+c)*256 + h
    const int t = threadIdx.x;
    const float* xr = x + (size_t)row * 256;
    a[t] = make_float2(__builtin_nontemporal_load(xr + t), 0.0f);
    __syncthreads();
#pragma unroll
    for (int s = 1; s <= 8; ++s) {
        const int half = 1 << (s - 1);
        const int p = t & ~half, q = p | half;
        const int j = t & (half - 1);
        const int rp = (s == 1) ? (int)brev8(p) : p;
        const int rq = (s == 1) ? (int)brev8(q) : q;
        float2 u = a[rp], v = a[rq];
        float sn, cs;
        __sincosf(-PI_F * (float)j / (float)half, &sn, &cs);
        float2 wv = make_float2(cs * v.x - sn * v.y, cs * v.y + sn * v.x);
        const float sig = (t & half) ? -1.0f : 1.0f;
        float2 o = make_float2(u.x + sig * wv.x, u.y + sig * wv.y);
        __syncthreads();
        a[t] = o;
        __syncthreads();
    }
    if (t <= 128) Xf[(size_t)row * 129 + t] = pack_bf(a[t].x, a[t].y);
}

// ------------- Pass 2/4: column FFT along H (in-place, tiled) ---------------
// Block = (b*64+c, w-tile of <=16 columns). LDS a[16][257] (padded).
__global__ __launch_bounds__(256) void k_colfft(unsigned* __restrict__ Xf,
                                                float sgn) {
    __shared__ float2 a[16][257];
    const int wt = blockIdx.x;
    const int w0 = wt * 16;
    const int TW = min(16, 129 - w0);
    const size_t base = (size_t)blockIdx.y * 33024;
    const int t = threadIdx.x;
    const int wl = t & 15, hb = t >> 4;

#pragma unroll
    for (int it = 0; it < 16; ++it) {
        const int h = it * 16 + hb;
        if (wl < TW) a[wl][h] = unpack_bf(Xf[base + (size_t)h * 129 + w0 + wl]);
    }
    __syncthreads();

#pragma unroll
    for (int s = 1; s <= 8; ++s) {
        const int half = 1 << (s - 1);
        const int p = t & ~half, q = p | half;
        const int j = t & (half - 1);
        const int rp = (s == 1) ? (int)brev8(p) : p;
        const int rq = (s == 1) ? (int)brev8(q) : q;
        float sn, cs;
        __sincosf(sgn * PI_F * (float)j / (float)half, &sn, &cs);
        const float sig = (t & half) ? -1.0f : 1.0f;
        float2 u[16], v[16];
#pragma unroll
        for (int c = 0; c < 16; ++c)
            if (c < TW) { u[c] = a[c][rp]; v[c] = a[c][rq]; }
        __syncthreads();
#pragma unroll
        for (int c = 0; c < 16; ++c)
            if (c < TW) {
                float2 wv = make_float2(cs * v[c].x - sn * v[c].y,
                                        cs * v[c].y + sn * v[c].x);
                a[c][t] = make_float2(u[c].x + sig * wv.x, u[c].y + sig * wv.y);
            }
        __syncthreads();
    }

#pragma unroll
    for (int it = 0; it < 16; ++it) {
        const int h = it * 16 + hb;
        if (wl < TW)
            Xf[base + (size_t)h * 129 + w0 + wl] = pack_bf(a[wl][h].x, a[wl][h].y);
    }
}

// --------------------- Pass 3: per-bin einsum (in-place) --------------------
// Z[b,i,n] = sum_o X[b,o,n] * W[o,i,n]   (W real), n = h*129+w flattened.
// Block = 32 consecutive n (one 128B line per row). 1032 blocks, no tail.
// Thread (nl = t&31, j = t>>5) accumulates i = r*8+j (r<8) x 8 batches.
__global__ __launch_bounds__(256) void k_einsum(unsigned* __restrict__ Xf,
                                                const float* __restrict__ Wt) {
    __shared__ unsigned xs[512][32];            // [(b<<6)|o][nl] = 64 KB
    const int t = threadIdx.x;
    // XCD-chunked swizzle: 1032 blocks = 8 XCD x 129.
    const int bid = blockIdx.x;
    const int nid = (bid & 7) * 129 + (bid >> 3);
    const size_t n0 = (size_t)nid * 32;

    // stage X[*, n0:n0+32] into LDS: 16 iters of uint4 per thread.
#pragma unroll
    for (int k = 0; k < 16; ++k) {
        const int e = t + 256 * k;
        const int pr = e >> 3, q = e & 7;
        const uint4 v = *reinterpret_cast<const uint4*>(
            Xf + (size_t)pr * 33024 + n0 + (q << 2));
        *reinterpret_cast<uint4*>(&xs[pr][q << 2]) = v;
    }
    __syncthreads();

    const int nl = t & 31, j = t >> 5;
    float2 acc[8][8];
#pragma unroll
    for (int r = 0; r < 8; ++r)
#pragma unroll
        for (int b = 0; b < 8; ++b) acc[r][b] = make_float2(0.0f, 0.0f);

    const float* Wb = Wt + n0 + nl;
    for (int o = 0; o < 64; ++o) {
        float2 xv[8];
#pragma unroll
        for (int b = 0; b < 8; ++b) xv[b] = unpack_bf(xs[(b << 6) | o][nl]);
#pragma unroll
        for (int r = 0; r < 8; ++r) {
            const int i = (r << 3) | j;
            const float wv = __builtin_nontemporal_load(
                Wb + (size_t)((o << 6) | i) * 33024);
#pragma unroll
            for (int b = 0; b < 8; ++b) {
                acc[r][b].x += xv[b].x * wv;
                acc[r][b].y += xv[b].y * wv;
            }
        }
    }

#pragma unroll
    for (int r = 0; r < 8; ++r) {
        const int i = (r << 3) | j;
#pragma unroll
        for (int b = 0; b < 8; ++b) {
            Xf[(size_t)((b << 6) | i) * 33024 + n0 + nl] =
                pack_bf(acc[r][b].x, acc[r][b].y);
        }
    }
}

// ------------- Pass 5: row irfft (129 complex -> 256 real) + bias -----------
__global__ __launch_bounds__(256) void k_rowifft(const unsigned* __restrict__ Zf,
                                                 const float* __restrict__ bias,
                                                 float* __restrict__ y) {
    __shared__ float2 a[256];
    const int row = blockIdx.x;                 // (b*64+i)*256 + h
    const int ci = (row >> 8) & 63;
    const int t = threadIdx.x;
    const unsigned* zr = Zf + (size_t)row * 129;
    if (t <= 128) {
        float2 v = unpack_bf(zr[t]);
        a[t] = v;
        if (t >= 1 && t <= 127) a[256 - t] = make_float2(v.x, -v.y);
    }
    __syncthreads();
#pragma unroll
    for (int s = 1; s <= 8; ++s) {
        const int half = 1 << (s - 1);
        const int p = t & ~half, q = p | half;
        const int j = t & (half - 1);
        const int rp = (s == 1) ? (int)brev8(p) : p;
        const int rq = (s == 1) ? (int)brev8(q) : q;
        float2 u = a[rp], v = a[rq];
        float sn, cs;
        __sincosf(PI_F * (float)j / (float)half, &sn, &cs);
        float2 wv = make_float2(cs * v.x - sn * v.y, cs * v.y + sn * v.x);
        const float sig = (t & half) ? -1.0f : 1.0f;
        float2 o = make_float2(u.x + sig * wv.x, u.y + sig * wv.y);
        __syncthreads();
        a[t] = o;
        __syncthreads();
    }
    const float b = bias[ci];
    __builtin_nontemporal_store(a[t].x * (1.0f / 65536.0f) + b,
                                y + (size_t)row * 256 + t);
}

// ---------------------------------------------------------------------------
extern "C" void kernel_launch(void* const* d_in, const int* in_sizes, int n_in,
                              void* d_out, int out_size, void* d_ws,
                              size_t ws_size, hipStream_t stream) {
    (void)in_sizes; (void)n_in; (void)out_size; (void)ws_size;
    const float* x    = (const float*)d_in[0];
    const float* wfft = (const float*)d_in[1];
    const float* bias = (const float*)d_in[2];
    float* y = (float*)d_out;
    unsigned* Xf = (unsigned*)d_ws;             // 512 x 33024 uint = 270 MB

    const int ROWS = 8 * 64 * 256;              // 131072

    k_rowfft<<<ROWS, 256, 0, stream>>>(x, Xf);
    k_colfft<<<dim3(9, 512), 256, 0, stream>>>(Xf, -1.0f);
    k_einsum<<<1032, 256, 0, stream>>>(Xf, wfft);
    k_colfft<<<dim3(9, 512), 256, 0, stream>>>(Xf, +1.0f);
    k_rowifft<<<ROWS, 256, 0, stream>>>(Xf, bias, y);
}

// Round 5
// 359.080 us; speedup vs baseline: 2.2008x; 1.5427x over previous
//
#include <hip/hip_runtime.h>
#include <hip/hip_bf16.h>
#include <math.h>

#define PI_F 3.14159265358979323846f

// ---------------------------------------------------------------------------
// x (8,64,256,256) f32; weight_fft (64,64,256,129) f32; bias (64) f32
// y (8,64,256,256) f32.
// Xf workspace: complex packed-bf16, [bo][n], n = h*129+w, 512 x 33024 x 4B.
// Round-5: fused 2D-FFT kernels. One block per (b,c) image; full spectrum
// S (256x129 packed bf16 = 129KB) lives in LDS; each 256-pt FFT is owned by
// ONE wave (radix-2^2, 4 LDS rounds, swizzled work tile) -> only 2
// __syncthreads per image. Deletes the P2/P4 global round-trips (1.08 GB).
// ---------------------------------------------------------------------------

__device__ __forceinline__ unsigned pack_bf(float re, float im) {
    unsigned ur = __float_as_uint(re);
    unsigned ui = __float_as_uint(im);
    ur = (ur + 0x7fffu + ((ur >> 16) & 1u)) >> 16;     // RNE to bf16
    ui = (ui + 0x7fffu + ((ui >> 16) & 1u)) & 0xffff0000u;
    return ur | ui;
}
__device__ __forceinline__ float2 unpack_bf(unsigned p) {
    return make_float2(__uint_as_float(p << 16),
                       __uint_as_float(p & 0xffff0000u));
}

// work-tile swizzle: spreads every round's b64 access evenly over bank pairs
__device__ __forceinline__ int s2i(int p) { return p ^ (((p >> 4) & 3) << 2); }

__device__ __forceinline__ float2 cadd(float2 a, float2 b){ return make_float2(a.x+b.x, a.y+b.y); }
__device__ __forceinline__ float2 csub(float2 a, float2 b){ return make_float2(a.x-b.x, a.y-b.y); }
__device__ __forceinline__ float2 cmul(float2 a, float2 b){ return make_float2(a.x*b.x-a.y*b.y, a.x*b.y+a.y*b.x); }

// two radix-2 stages (s, s+1) on quad {p, p+h, p+2h, p+3h}; jt = p & (h-1)
template<int SGN>
__device__ __forceinline__ void quad2(float2& u0, float2& u1, float2& u2, float2& u3,
                                      int jt, float invh) {
    const float th = (SGN < 0 ? -PI_F : PI_F) * (float)jt * invh;
    float s1, c1, s2v, c2;
    __sincosf(th, &s1, &c1);
    __sincosf(0.5f * th, &s2v, &c2);
    const float2 w1 = make_float2(c1, s1), w2 = make_float2(c2, s2v);
    const float2 t1 = cmul(w1, u1), t3 = cmul(w1, u3);
    const float2 v0 = cadd(u0, t1), v1 = csub(u0, t1);
    const float2 v2 = cadd(u2, t3), v3 = csub(u2, t3);
    const float2 t2 = cmul(w2, v2);
    float2 t4 = cmul(w2, v3);
    t4 = (SGN < 0) ? make_float2(t4.y, -t4.x) : make_float2(-t4.y, t4.x);
    u0 = cadd(v0, t2); u2 = csub(v0, t2);
    u1 = cadd(v1, t4); u3 = csub(v1, t4);
}

// 256-pt FFT by one wave. Input in natural order in w (s2i-swizzled).
// Outputs at natural positions j, j+64, j+128, j+192 returned in registers.
// Caller must wave_barrier() between its staging writes and this call.
template<int SGN>
__device__ __forceinline__ void fft256(float2* w, int j,
                                       float2& o0, float2& o1, float2& o2, float2& o3) {
    // round 1 (stages 1-2): bit-reversed reads, trivial twiddles
    const int r = (int)(__brev((unsigned)j) >> 26);           // brev6
    float2 u0 = w[s2i(r)], u1 = w[s2i(r + 128)], u2 = w[s2i(r + 64)], u3 = w[s2i(r + 192)];
    __builtin_amdgcn_wave_barrier();                          // reads before writes
    {
        const float2 v0 = cadd(u0, u1), v1 = csub(u0, u1);
        const float2 v2 = cadd(u2, u3), v3 = csub(u2, u3);
        const float2 t4 = (SGN < 0) ? make_float2(v3.y, -v3.x) : make_float2(-v3.y, v3.x);
        u0 = cadd(v0, v2); u2 = csub(v0, v2);
        u1 = cadd(v1, t4); u3 = csub(v1, t4);
    }
    const int p4 = s2i(4 * j);                                // contiguous block of 4
    *(float4*)&w[p4]     = make_float4(u0.x, u0.y, u1.x, u1.y);
    *(float4*)&w[p4 + 2] = make_float4(u2.x, u2.y, u3.x, u3.y);
    __builtin_amdgcn_wave_barrier();
    // round 2 (stages 3-4): h=4
    {
        const int jt = j & 3;
        const int p = ((j >> 2) << 4) | jt;
        float2 a0 = w[s2i(p)], a1 = w[s2i(p+4)], a2 = w[s2i(p+8)], a3 = w[s2i(p+12)];
        quad2<SGN>(a0, a1, a2, a3, jt, 0.25f);
        w[s2i(p)] = a0; w[s2i(p+4)] = a1; w[s2i(p+8)] = a2; w[s2i(p+12)] = a3;
    }
    __builtin_amdgcn_wave_barrier();
    // round 3 (stages 5-6): h=16
    {
        const int jt = j & 15;
        const int p = ((j >> 4) << 6) | jt;
        float2 a0 = w[s2i(p)], a1 = w[s2i(p+16)], a2 = w[s2i(p+32)], a3 = w[s2i(p+48)];
        quad2<SGN>(a0, a1, a2, a3, jt, 1.0f/16.0f);
        w[s2i(p)] = a0; w[s2i(p+16)] = a1; w[s2i(p+32)] = a2; w[s2i(p+48)] = a3;
    }
    __builtin_amdgcn_wave_barrier();
    // round 4 (stages 7-8): h=64
    {
        float2 a0 = w[s2i(j)], a1 = w[s2i(j+64)], a2 = w[s2i(j+128)], a3 = w[s2i(j+192)];
        quad2<SGN>(a0, a1, a2, a3, j, 1.0f/64.0f);
        o0 = a0; o1 = a1; o2 = a2; o3 = a3;
    }
}

#define SMEM_BYTES (132096 + 8 * 256 * 8)   // S (33024 u32) + 8 wave tiles

// ------------------- K1: fused row-rFFT + col-FFT per image -----------------
__global__ __launch_bounds__(512) void k_fwd2d(const float* __restrict__ x,
                                               unsigned* __restrict__ Xf) {
    extern __shared__ char smem[];
    unsigned* S = (unsigned*)smem;
    float2* w = (float2*)(smem + 132096) + ((threadIdx.x >> 6) << 8);
    const int t = threadIdx.x, f = t >> 6, j = t & 63;
    const int bo = blockIdx.x;
    const float* xi = x + (size_t)bo * 65536;

    // row phase: wave f does rows f, f+8, ...
    for (int r = f; r < 256; r += 8) {
        const float4 v = ((const float4*)(xi + (r << 8)))[j];
        const int p4 = s2i(4 * j);
        *(float4*)&w[p4]     = make_float4(v.x, 0.0f, v.y, 0.0f);
        *(float4*)&w[p4 + 2] = make_float4(v.z, 0.0f, v.w, 0.0f);
        __builtin_amdgcn_wave_barrier();
        float2 o0, o1, o2, o3;
        fft256<-1>(w, j, o0, o1, o2, o3);
        S[r * 129 + j]      = pack_bf(o0.x, o0.y);
        S[r * 129 + 64 + j] = pack_bf(o1.x, o1.y);
        if (j == 0) S[r * 129 + 128] = pack_bf(o2.x, o2.y);
        __builtin_amdgcn_wave_barrier();
    }
    __syncthreads();
    // col phase: wave f does cols f, f+8, ...
    for (int c = f; c <= 128; c += 8) {
#pragma unroll
        for (int k = 0; k < 4; ++k)
            w[s2i(j + 64 * k)] = unpack_bf(S[(j + 64 * k) * 129 + c]);
        __builtin_amdgcn_wave_barrier();
        float2 o0, o1, o2, o3;
        fft256<-1>(w, j, o0, o1, o2, o3);
        S[(j      ) * 129 + c] = pack_bf(o0.x, o0.y);
        S[(j +  64) * 129 + c] = pack_bf(o1.x, o1.y);
        S[(j + 128) * 129 + c] = pack_bf(o2.x, o2.y);
        S[(j + 192) * 129 + c] = pack_bf(o3.x, o3.y);
        __builtin_amdgcn_wave_barrier();
    }
    __syncthreads();
    // dump S -> Xf[bo]
    uint4* dst = (uint4*)(Xf + (size_t)bo * 33024);
    const uint4* src = (const uint4*)S;
    for (int e = t; e < 8256; e += 512) dst[e] = src[e];
}

// --------------------- K2: per-bin einsum (in-place, rd4) -------------------
__global__ __launch_bounds__(256) void k_einsum(unsigned* __restrict__ Xf,
                                                const float* __restrict__ Wt) {
    __shared__ unsigned xs[512][32];            // [(b<<6)|o][nl] = 64 KB
    const int t = threadIdx.x;
    const int bid = blockIdx.x;                 // 1032 = 8 XCD x 129
    const int nid = (bid & 7) * 129 + (bid >> 3);
    const size_t n0 = (size_t)nid * 32;

#pragma unroll
    for (int k = 0; k < 16; ++k) {
        const int e = t + 256 * k;
        const int pr = e >> 3, q = e & 7;
        const uint4 v = *reinterpret_cast<const uint4*>(
            Xf + (size_t)pr * 33024 + n0 + (q << 2));
        *reinterpret_cast<uint4*>(&xs[pr][q << 2]) = v;
    }
    __syncthreads();

    const int nl = t & 31, j = t >> 5;
    float2 acc[8][8];
#pragma unroll
    for (int r = 0; r < 8; ++r)
#pragma unroll
        for (int b = 0; b < 8; ++b) acc[r][b] = make_float2(0.0f, 0.0f);

    const float* Wb = Wt + n0 + nl;
    for (int o = 0; o < 64; ++o) {
        float2 xv[8];
#pragma unroll
        for (int b = 0; b < 8; ++b) xv[b] = unpack_bf(xs[(b << 6) | o][nl]);
#pragma unroll
        for (int r = 0; r < 8; ++r) {
            const int i = (r << 3) | j;
            const float wv = __builtin_nontemporal_load(
                Wb + (size_t)((o << 6) | i) * 33024);
#pragma unroll
            for (int b = 0; b < 8; ++b) {
                acc[r][b].x += xv[b].x * wv;
                acc[r][b].y += xv[b].y * wv;
            }
        }
    }

#pragma unroll
    for (int r = 0; r < 8; ++r) {
        const int i = (r << 3) | j;
#pragma unroll
        for (int b = 0; b < 8; ++b) {
            Xf[(size_t)((b << 6) | i) * 33024 + n0 + nl] =
                pack_bf(acc[r][b].x, acc[r][b].y);
        }
    }
}

// ------------- K3: fused col-iFFT + row-irFFT (+bias) per image -------------
__global__ __launch_bounds__(512) void k_inv2d(const unsigned* __restrict__ Xf,
                                               const float* __restrict__ bias,
                                               float* __restrict__ y) {
    extern __shared__ char smem[];
    unsigned* S = (unsigned*)smem;
    float2* w = (float2*)(smem + 132096) + ((threadIdx.x >> 6) << 8);
    const int t = threadIdx.x, f = t >> 6, j = t & 63;
    const int bo = blockIdx.x;
    const float bv = bias[bo & 63];

    // load Xf[bo] -> S
    {
        uint4* s4 = (uint4*)S;
        const uint4* g4 = (const uint4*)(Xf + (size_t)bo * 33024);
        for (int e = t; e < 8256; e += 512) s4[e] = g4[e];
    }
    __syncthreads();
    // col inverse phase
    for (int c = f; c <= 128; c += 8) {
#pragma unroll
        for (int k = 0; k < 4; ++k)
            w[s2i(j + 64 * k)] = unpack_bf(S[(j + 64 * k) * 129 + c]);
        __builtin_amdgcn_wave_barrier();
        float2 o0, o1, o2, o3;
        fft256<+1>(w, j, o0, o1, o2, o3);
        S[(j      ) * 129 + c] = pack_bf(o0.x, o0.y);
        S[(j +  64) * 129 + c] = pack_bf(o1.x, o1.y);
        S[(j + 128) * 129 + c] = pack_bf(o2.x, o2.y);
        S[(j + 192) * 129 + c] = pack_bf(o3.x, o3.y);
        __builtin_amdgcn_wave_barrier();
    }
    __syncthreads();
    // row inverse phase with Hermitian extension; write y from registers
    float* yo = y + (size_t)bo * 65536;
    for (int r = f; r < 256; r += 8) {
        const unsigned* Sr = S + r * 129;
        float2 a0 = unpack_bf(Sr[j]);
        float2 a1 = unpack_bf(Sr[j + 64]);
        float2 a2;
        if (j == 0) a2 = unpack_bf(Sr[128]);
        else { a2 = unpack_bf(Sr[128 - j]); a2.y = -a2.y; }
        float2 a3 = unpack_bf(Sr[64 - j]); a3.y = -a3.y;
        w[s2i(j)]       = a0;
        w[s2i(j +  64)] = a1;
        w[s2i(j + 128)] = a2;
        w[s2i(j + 192)] = a3;
        __builtin_amdgcn_wave_barrier();
        float2 o0, o1, o2, o3;
        fft256<+1>(w, j, o0, o1, o2, o3);
        const float sc = 1.0f / 65536.0f;
        float* yr = yo + (r << 8);
        __builtin_nontemporal_store(o0.x * sc + bv, yr + j);
        __builtin_nontemporal_store(o1.x * sc + bv, yr + j + 64);
        __builtin_nontemporal_store(o2.x * sc + bv, yr + j + 128);
        __builtin_nontemporal_store(o3.x * sc + bv, yr + j + 192);
        __builtin_amdgcn_wave_barrier();
    }
}

// ---------------------------------------------------------------------------
extern "C" void kernel_launch(void* const* d_in, const int* in_sizes, int n_in,
                              void* d_out, int out_size, void* d_ws,
                              size_t ws_size, hipStream_t stream) {
    (void)in_sizes; (void)n_in; (void)out_size; (void)ws_size;
    const float* x    = (const float*)d_in[0];
    const float* wfft = (const float*)d_in[1];
    const float* bias = (const float*)d_in[2];
    float* y = (float*)d_out;
    unsigned* Xf = (unsigned*)d_ws;             // 512 x 33024 uint = 270 MB

    hipFuncSetAttribute((const void*)k_fwd2d,
                        hipFuncAttributeMaxDynamicSharedMemorySize, SMEM_BYTES);
    hipFuncSetAttribute((const void*)k_inv2d,
                        hipFuncAttributeMaxDynamicSharedMemorySize, SMEM_BYTES);

    k_fwd2d<<<512, 512, SMEM_BYTES, stream>>>(x, Xf);
    k_einsum<<<1032, 256, 0, stream>>>(Xf, wfft);
    k_inv2d<<<512, 512, SMEM_BYTES, stream>>>(Xf, bias, y);
}

// Round 7
// 333.430 us; speedup vs baseline: 2.3701x; 1.0769x over previous
//
#include <hip/hip_runtime.h>
#include <hip/hip_bf16.h>
#include <math.h>

#define PI_F 3.14159265358979323846f

// ---------------------------------------------------------------------------
// x (8,64,256,256) f32; weight_fft (64,64,256,129) f32; bias (64) f32
// y (8,64,256,256) f32.
// Xf workspace: complex packed-bf16, [bo][n], n = h*129+w, 512 x 33024 x 4B
// (67.6 MB -> L3-resident). All arithmetic fp32; inter-pass storage bf16.
// Round-7: BISECT of rd6 failure. Row phases reverted to rd5 (unpaired,
// known-good). Kept: (a) einsum depth-2 W register prefetch, (c) quad2
// single-sincos + double-angle.
// ---------------------------------------------------------------------------

__device__ __forceinline__ unsigned pack_bf(float re, float im) {
    unsigned ur = __float_as_uint(re);
    unsigned ui = __float_as_uint(im);
    ur = (ur + 0x7fffu + ((ur >> 16) & 1u)) >> 16;     // RNE to bf16
    ui = (ui + 0x7fffu + ((ui >> 16) & 1u)) & 0xffff0000u;
    return ur | ui;
}
__device__ __forceinline__ float2 unpack_bf(unsigned p) {
    return make_float2(__uint_as_float(p << 16),
                       __uint_as_float(p & 0xffff0000u));
}

// work-tile swizzle: spreads every round's b64 access evenly over bank pairs
__device__ __forceinline__ int s2i(int p) { return p ^ (((p >> 4) & 3) << 2); }

__device__ __forceinline__ float2 cadd(float2 a, float2 b){ return make_float2(a.x+b.x, a.y+b.y); }
__device__ __forceinline__ float2 csub(float2 a, float2 b){ return make_float2(a.x-b.x, a.y-b.y); }
__device__ __forceinline__ float2 cmul(float2 a, float2 b){ return make_float2(a.x*b.x-a.y*b.y, a.x*b.y+a.y*b.x); }

// two radix-2 stages (s, s+1) on quad {p, p+h, p+2h, p+3h}; jt = p & (h-1)
template<int SGN>
__device__ __forceinline__ void quad2(float2& u0, float2& u1, float2& u2, float2& u3,
                                      int jt, float invh) {
    const float th = (SGN < 0 ? -PI_F : PI_F) * (float)jt * invh;
    float s2v, c2;
    __sincosf(0.5f * th, &s2v, &c2);                    // w2 = e^{i th/2}
    const float c1 = c2 * c2 - s2v * s2v;               // w1 = w2^2 (exact identity)
    const float s1 = 2.0f * c2 * s2v;
    const float2 w1 = make_float2(c1, s1), w2 = make_float2(c2, s2v);
    const float2 t1 = cmul(w1, u1), t3 = cmul(w1, u3);
    const float2 v0 = cadd(u0, t1), v1 = csub(u0, t1);
    const float2 v2 = cadd(u2, t3), v3 = csub(u2, t3);
    const float2 t2 = cmul(w2, v2);
    float2 t4 = cmul(w2, v3);
    t4 = (SGN < 0) ? make_float2(t4.y, -t4.x) : make_float2(-t4.y, t4.x);
    u0 = cadd(v0, t2); u2 = csub(v0, t2);
    u1 = cadd(v1, t4); u3 = csub(v1, t4);
}

// 256-pt FFT by one wave. Input in natural order in w (s2i-swizzled).
// Outputs at natural positions j, j+64, j+128, j+192 returned in registers.
// Caller must wave_barrier() between its staging writes and this call.
template<int SGN>
__device__ __forceinline__ void fft256(float2* w, int j,
                                       float2& o0, float2& o1, float2& o2, float2& o3) {
    // round 1 (stages 1-2): bit-reversed reads, trivial twiddles
    const int r = (int)(__brev((unsigned)j) >> 26);           // brev6
    float2 u0 = w[s2i(r)], u1 = w[s2i(r + 128)], u2 = w[s2i(r + 64)], u3 = w[s2i(r + 192)];
    __builtin_amdgcn_wave_barrier();                          // reads before writes
    {
        const float2 v0 = cadd(u0, u1), v1 = csub(u0, u1);
        const float2 v2 = cadd(u2, u3), v3 = csub(u2, u3);
        const float2 t4 = (SGN < 0) ? make_float2(v3.y, -v3.x) : make_float2(-v3.y, v3.x);
        u0 = cadd(v0, v2); u2 = csub(v0, v2);
        u1 = cadd(v1, t4); u3 = csub(v1, t4);
    }
    const int p4 = s2i(4 * j);                                // contiguous block of 4
    *(float4*)&w[p4]     = make_float4(u0.x, u0.y, u1.x, u1.y);
    *(float4*)&w[p4 + 2] = make_float4(u2.x, u2.y, u3.x, u3.y);
    __builtin_amdgcn_wave_barrier();
    // round 2 (stages 3-4): h=4
    {
        const int jt = j & 3;
        const int p = ((j >> 2) << 4) | jt;
        float2 a0 = w[s2i(p)], a1 = w[s2i(p+4)], a2 = w[s2i(p+8)], a3 = w[s2i(p+12)];
        quad2<SGN>(a0, a1, a2, a3, jt, 0.25f);
        w[s2i(p)] = a0; w[s2i(p+4)] = a1; w[s2i(p+8)] = a2; w[s2i(p+12)] = a3;
    }
    __builtin_amdgcn_wave_barrier();
    // round 3 (stages 5-6): h=16
    {
        const int jt = j & 15;
        const int p = ((j >> 4) << 6) | jt;
        float2 a0 = w[s2i(p)], a1 = w[s2i(p+16)], a2 = w[s2i(p+32)], a3 = w[s2i(p+48)];
        quad2<SGN>(a0, a1, a2, a3, jt, 1.0f/16.0f);
        w[s2i(p)] = a0; w[s2i(p+16)] = a1; w[s2i(p+32)] = a2; w[s2i(p+48)] = a3;
    }
    __builtin_amdgcn_wave_barrier();
    // round 4 (stages 7-8): h=64
    {
        float2 a0 = w[s2i(j)], a1 = w[s2i(j+64)], a2 = w[s2i(j+128)], a3 = w[s2i(j+192)];
        quad2<SGN>(a0, a1, a2, a3, j, 1.0f/64.0f);
        o0 = a0; o1 = a1; o2 = a2; o3 = a3;
    }
}

#define SMEM_BYTES (132096 + 8 * 256 * 8)   // S (33024 u32) + 8 wave tiles

// ------------------- K1: fused row-rFFT + col-FFT per image -----------------
__global__ __launch_bounds__(512) void k_fwd2d(const float* __restrict__ x,
                                               unsigned* __restrict__ Xf) {
    extern __shared__ char smem[];
    unsigned* S = (unsigned*)smem;
    float2* w = (float2*)(smem + 132096) + ((threadIdx.x >> 6) << 8);
    const int t = threadIdx.x, f = t >> 6, j = t & 63;
    const int bo = blockIdx.x;
    const float* xi = x + (size_t)bo * 65536;

    // row phase (rd5 known-good): wave f does rows f, f+8, ...
    for (int r = f; r < 256; r += 8) {
        const float4 v = ((const float4*)(xi + (r << 8)))[j];
        const int p4 = s2i(4 * j);
        *(float4*)&w[p4]     = make_float4(v.x, 0.0f, v.y, 0.0f);
        *(float4*)&w[p4 + 2] = make_float4(v.z, 0.0f, v.w, 0.0f);
        __builtin_amdgcn_wave_barrier();
        float2 o0, o1, o2, o3;
        fft256<-1>(w, j, o0, o1, o2, o3);
        S[r * 129 + j]      = pack_bf(o0.x, o0.y);
        S[r * 129 + 64 + j] = pack_bf(o1.x, o1.y);
        if (j == 0) S[r * 129 + 128] = pack_bf(o2.x, o2.y);
        __builtin_amdgcn_wave_barrier();
    }
    __syncthreads();
    // col phase: wave f does cols f, f+8, ...
    for (int c = f; c <= 128; c += 8) {
#pragma unroll
        for (int k = 0; k < 4; ++k)
            w[s2i(j + 64 * k)] = unpack_bf(S[(j + 64 * k) * 129 + c]);
        __builtin_amdgcn_wave_barrier();
        float2 o0, o1, o2, o3;
        fft256<-1>(w, j, o0, o1, o2, o3);
        S[(j      ) * 129 + c] = pack_bf(o0.x, o0.y);
        S[(j +  64) * 129 + c] = pack_bf(o1.x, o1.y);
        S[(j + 128) * 129 + c] = pack_bf(o2.x, o2.y);
        S[(j + 192) * 129 + c] = pack_bf(o3.x, o3.y);
        __builtin_amdgcn_wave_barrier();
    }
    __syncthreads();
    // dump S -> Xf[bo]
    uint4* dst = (uint4*)(Xf + (size_t)bo * 33024);
    const uint4* src4 = (const uint4*)S;
    for (int e = t; e < 8256; e += 512) dst[e] = src4[e];
}

// --------------------- K2: per-bin einsum (in-place) ------------------------
// Z[b,i,n] = sum_o X[b,o,n] * W[o,i,n], n flat = h*129+w. Block = 32 n (one
// 128B line). Depth-2 register prefetch of W hides HBM latency.
__global__ __launch_bounds__(256) void k_einsum(unsigned* __restrict__ Xf,
                                                const float* __restrict__ Wt) {
    __shared__ unsigned xs[512][32];            // [(b<<6)|o][nl] = 64 KB
    const int t = threadIdx.x;
    const int bid = blockIdx.x;                 // 1032 = 8 XCD x 129
    const int nid = (bid & 7) * 129 + (bid >> 3);
    const size_t n0 = (size_t)nid * 32;

#pragma unroll
    for (int k = 0; k < 16; ++k) {
        const int e = t + 256 * k;
        const int pr = e >> 3, q = e & 7;
        const uint4 v = *reinterpret_cast<const uint4*>(
            Xf + (size_t)pr * 33024 + n0 + (q << 2));
        *reinterpret_cast<uint4*>(&xs[pr][q << 2]) = v;
    }
    __syncthreads();

    const int nl = t & 31, j = t >> 5;
    float2 acc[8][8];
#pragma unroll
    for (int r = 0; r < 8; ++r)
#pragma unroll
        for (int b = 0; b < 8; ++b) acc[r][b] = make_float2(0.0f, 0.0f);

    const float* Wb = Wt + n0 + nl;
    auto wload = [&](int o, float (&buf)[8]) {
#pragma unroll
        for (int r = 0; r < 8; ++r)
            buf[r] = __builtin_nontemporal_load(
                Wb + (size_t)((o << 6) | ((r << 3) | j)) * 33024);
    };
    auto fmab = [&](int o, const float (&wc)[8]) {
        float2 xv[8];
#pragma unroll
        for (int b = 0; b < 8; ++b) xv[b] = unpack_bf(xs[(b << 6) | o][nl]);
#pragma unroll
        for (int r = 0; r < 8; ++r)
#pragma unroll
            for (int b = 0; b < 8; ++b) {
                acc[r][b].x += xv[b].x * wc[r];
                acc[r][b].y += xv[b].y * wc[r];
            }
    };

    float wA[8], wB[8];
    wload(0, wA);
    wload(1, wB);
    for (int o = 0; o < 64; o += 2) {
        float wc0[8];
#pragma unroll
        for (int r = 0; r < 8; ++r) wc0[r] = wA[r];
        wload((o + 2) & 63, wA);                // depth-2 prefetch (wraps: cheap)
        fmab(o, wc0);
        float wc1[8];
#pragma unroll
        for (int r = 0; r < 8; ++r) wc1[r] = wB[r];
        wload((o + 3) & 63, wB);
        fmab(o + 1, wc1);
    }

#pragma unroll
    for (int r = 0; r < 8; ++r) {
        const int i = (r << 3) | j;
#pragma unroll
        for (int b = 0; b < 8; ++b) {
            Xf[(size_t)((b << 6) | i) * 33024 + n0 + nl] =
                pack_bf(acc[r][b].x, acc[r][b].y);
        }
    }
}

// ------------- K3: fused col-iFFT + row-irFFT (+bias) per image -------------
__global__ __launch_bounds__(512) void k_inv2d(const unsigned* __restrict__ Xf,
                                               const float* __restrict__ bias,
                                               float* __restrict__ y) {
    extern __shared__ char smem[];
    unsigned* S = (unsigned*)smem;
    float2* w = (float2*)(smem + 132096) + ((threadIdx.x >> 6) << 8);
    const int t = threadIdx.x, f = t >> 6, j = t & 63;
    const int bo = blockIdx.x;
    const float bv = bias[bo & 63];

    // load Xf[bo] -> S
    {
        uint4* s4 = (uint4*)S;
        const uint4* g4 = (const uint4*)(Xf + (size_t)bo * 33024);
        for (int e = t; e < 8256; e += 512) s4[e] = g4[e];
    }
    __syncthreads();
    // col inverse phase
    for (int c = f; c <= 128; c += 8) {
#pragma unroll
        for (int k = 0; k < 4; ++k)
            w[s2i(j + 64 * k)] = unpack_bf(S[(j + 64 * k) * 129 + c]);
        __builtin_amdgcn_wave_barrier();
        float2 o0, o1, o2, o3;
        fft256<+1>(w, j, o0, o1, o2, o3);
        S[(j      ) * 129 + c] = pack_bf(o0.x, o0.y);
        S[(j +  64) * 129 + c] = pack_bf(o1.x, o1.y);
        S[(j + 128) * 129 + c] = pack_bf(o2.x, o2.y);
        S[(j + 192) * 129 + c] = pack_bf(o3.x, o3.y);
        __builtin_amdgcn_wave_barrier();
    }
    __syncthreads();
    // row inverse phase (rd5 known-good): Hermitian extension, Re -> y
    float* yo = y + (size_t)bo * 65536;
    for (int r = f; r < 256; r += 8) {
        const unsigned* Sr = S + r * 129;
        float2 a0 = unpack_bf(Sr[j]);
        float2 a1 = unpack_bf(Sr[j + 64]);
        float2 a2;
        if (j == 0) a2 = unpack_bf(Sr[128]);
        else { a2 = unpack_bf(Sr[128 - j]); a2.y = -a2.y; }
        float2 a3 = unpack_bf(Sr[64 - j]); a3.y = -a3.y;
        w[s2i(j)]       = a0;
        w[s2i(j +  64)] = a1;
        w[s2i(j + 128)] = a2;
        w[s2i(j + 192)] = a3;
        __builtin_amdgcn_wave_barrier();
        float2 o0, o1, o2, o3;
        fft256<+1>(w, j, o0, o1, o2, o3);
        const float sc = 1.0f / 65536.0f;
        float* yr = yo + (r << 8);
        __builtin_nontemporal_store(o0.x * sc + bv, yr + j);
        __builtin_nontemporal_store(o1.x * sc + bv, yr + j + 64);
        __builtin_nontemporal_store(o2.x * sc + bv, yr + j + 128);
        __builtin_nontemporal_store(o3.x * sc + bv, yr + j + 192);
        __builtin_amdgcn_wave_barrier();
    }
}

// ---------------------------------------------------------------------------
extern "C" void kernel_launch(void* const* d_in, const int* in_sizes, int n_in,
                              void* d_out, int out_size, void* d_ws,
                              size_t ws_size, hipStream_t stream) {
    (void)in_sizes; (void)n_in; (void)out_size; (void)ws_size;
    const float* x    = (const float*)d_in[0];
    const float* wfft = (const float*)d_in[1];
    const float* bias = (const float*)d_in[2];
    float* y = (float*)d_out;
    unsigned* Xf = (unsigned*)d_ws;             // 512 x 33024 uint = 67.6 MB

    hipFuncSetAttribute((const void*)k_fwd2d,
                        hipFuncAttributeMaxDynamicSharedMemorySize, SMEM_BYTES);
    hipFuncSetAttribute((const void*)k_inv2d,
                        hipFuncAttributeMaxDynamicSharedMemorySize, SMEM_BYTES);

    k_fwd2d<<<512, 512, SMEM_BYTES, stream>>>(x, Xf);
    k_einsum<<<1032, 256, 0, stream>>>(Xf, wfft);
    k_inv2d<<<512, 512, SMEM_BYTES, stream>>>(Xf, bias, y);
}

// Round 8
// 286.609 us; speedup vs baseline: 2.7573x; 1.1634x over previous
//
#include <hip/hip_runtime.h>
#include <hip/hip_bf16.h>
#include <math.h>

#define PI_F 3.14159265358979323846f

// ---------------------------------------------------------------------------
// x (8,64,256,256) f32; weight_fft (64,64,256,129) f32; bias (64) f32
// y (8,64,256,256) f32.
// Xf workspace: complex packed-bf16, [bo][n], n = h*129+w, 512 x 33024 x 4B
// (67.6 MB -> L3-resident). All arithmetic fp32; inter-pass storage bf16.
// Round-8: restore real-pair row FFT trick (fwd + inv). Root cause of rd6
// fail: after einsum the spectra are NOT Hermitian in h, so A,B carry genuine
// imaginary content at self-conjugate bins k=0,128; reference irfft projects
// it away. Fix: inverse pairing zeroes Im(A),Im(B) at k=0 and k=128 (exact
// projection), all other bins conj-reflected by construction.
// ---------------------------------------------------------------------------

__device__ __forceinline__ unsigned pack_bf(float re, float im) {
    unsigned ur = __float_as_uint(re);
    unsigned ui = __float_as_uint(im);
    ur = (ur + 0x7fffu + ((ur >> 16) & 1u)) >> 16;     // RNE to bf16
    ui = (ui + 0x7fffu + ((ui >> 16) & 1u)) & 0xffff0000u;
    return ur | ui;
}
__device__ __forceinline__ float2 unpack_bf(unsigned p) {
    return make_float2(__uint_as_float(p << 16),
                       __uint_as_float(p & 0xffff0000u));
}

// work-tile swizzle: spreads every round's b64 access evenly over bank pairs
__device__ __forceinline__ int s2i(int p) { return p ^ (((p >> 4) & 3) << 2); }

__device__ __forceinline__ float2 cadd(float2 a, float2 b){ return make_float2(a.x+b.x, a.y+b.y); }
__device__ __forceinline__ float2 csub(float2 a, float2 b){ return make_float2(a.x-b.x, a.y-b.y); }
__device__ __forceinline__ float2 cmul(float2 a, float2 b){ return make_float2(a.x*b.x-a.y*b.y, a.x*b.y+a.y*b.x); }

// two radix-2 stages (s, s+1) on quad {p, p+h, p+2h, p+3h}; jt = p & (h-1)
template<int SGN>
__device__ __forceinline__ void quad2(float2& u0, float2& u1, float2& u2, float2& u3,
                                      int jt, float invh) {
    const float th = (SGN < 0 ? -PI_F : PI_F) * (float)jt * invh;
    float s2v, c2;
    __sincosf(0.5f * th, &s2v, &c2);                    // w2 = e^{i th/2}
    const float c1 = c2 * c2 - s2v * s2v;               // w1 = w2^2 (exact identity)
    const float s1 = 2.0f * c2 * s2v;
    const float2 w1 = make_float2(c1, s1), w2 = make_float2(c2, s2v);
    const float2 t1 = cmul(w1, u1), t3 = cmul(w1, u3);
    const float2 v0 = cadd(u0, t1), v1 = csub(u0, t1);
    const float2 v2 = cadd(u2, t3), v3 = csub(u2, t3);
    const float2 t2 = cmul(w2, v2);
    float2 t4 = cmul(w2, v3);
    t4 = (SGN < 0) ? make_float2(t4.y, -t4.x) : make_float2(-t4.y, t4.x);
    u0 = cadd(v0, t2); u2 = csub(v0, t2);
    u1 = cadd(v1, t4); u3 = csub(v1, t4);
}

// 256-pt FFT by one wave. Input in natural order in w (s2i-swizzled).
// Outputs at natural positions j, j+64, j+128, j+192 returned in registers.
// Caller must wave_barrier() between its staging writes and this call.
template<int SGN>
__device__ __forceinline__ void fft256(float2* w, int j,
                                       float2& o0, float2& o1, float2& o2, float2& o3) {
    // round 1 (stages 1-2): bit-reversed reads, trivial twiddles
    const int r = (int)(__brev((unsigned)j) >> 26);           // brev6
    float2 u0 = w[s2i(r)], u1 = w[s2i(r + 128)], u2 = w[s2i(r + 64)], u3 = w[s2i(r + 192)];
    __builtin_amdgcn_wave_barrier();                          // reads before writes
    {
        const float2 v0 = cadd(u0, u1), v1 = csub(u0, u1);
        const float2 v2 = cadd(u2, u3), v3 = csub(u2, u3);
        const float2 t4 = (SGN < 0) ? make_float2(v3.y, -v3.x) : make_float2(-v3.y, v3.x);
        u0 = cadd(v0, v2); u2 = csub(v0, v2);
        u1 = cadd(v1, t4); u3 = csub(v1, t4);
    }
    const int p4 = s2i(4 * j);                                // contiguous block of 4
    *(float4*)&w[p4]     = make_float4(u0.x, u0.y, u1.x, u1.y);
    *(float4*)&w[p4 + 2] = make_float4(u2.x, u2.y, u3.x, u3.y);
    __builtin_amdgcn_wave_barrier();
    // round 2 (stages 3-4): h=4
    {
        const int jt = j & 3;
        const int p = ((j >> 2) << 4) | jt;
        float2 a0 = w[s2i(p)], a1 = w[s2i(p+4)], a2 = w[s2i(p+8)], a3 = w[s2i(p+12)];
        quad2<SGN>(a0, a1, a2, a3, jt, 0.25f);
        w[s2i(p)] = a0; w[s2i(p+4)] = a1; w[s2i(p+8)] = a2; w[s2i(p+12)] = a3;
    }
    __builtin_amdgcn_wave_barrier();
    // round 3 (stages 5-6): h=16
    {
        const int jt = j & 15;
        const int p = ((j >> 4) << 6) | jt;
        float2 a0 = w[s2i(p)], a1 = w[s2i(p+16)], a2 = w[s2i(p+32)], a3 = w[s2i(p+48)];
        quad2<SGN>(a0, a1, a2, a3, jt, 1.0f/16.0f);
        w[s2i(p)] = a0; w[s2i(p+16)] = a1; w[s2i(p+32)] = a2; w[s2i(p+48)] = a3;
    }
    __builtin_amdgcn_wave_barrier();
    // round 4 (stages 7-8): h=64
    {
        float2 a0 = w[s2i(j)], a1 = w[s2i(j+64)], a2 = w[s2i(j+128)], a3 = w[s2i(j+192)];
        quad2<SGN>(a0, a1, a2, a3, j, 1.0f/64.0f);
        o0 = a0; o1 = a1; o2 = a2; o3 = a3;
    }
}

#define SMEM_BYTES (132096 + 8 * 256 * 8)   // S (33024 u32) + 8 wave tiles

// ------------------- K1: fused row-rFFT + col-FFT per image -----------------
__global__ __launch_bounds__(512) void k_fwd2d(const float* __restrict__ x,
                                               unsigned* __restrict__ Xf) {
    extern __shared__ char smem[];
    unsigned* S = (unsigned*)smem;
    float2* w = (float2*)(smem + 132096) + ((threadIdx.x >> 6) << 8);
    const int t = threadIdx.x, f = t >> 6, j = t & 63;
    const int bo = blockIdx.x;
    const float* xi = x + (size_t)bo * 65536;

    // row phase (paired): wave f does row pairs (rp, rp+128). Rows are real,
    // so z = row1 + i*row2, one FFT, separate via conj-partner exchange.
    for (int rp = f; rp < 128; rp += 8) {
        const int r1 = rp, r2 = rp + 128;
        const float4 va = ((const float4*)(xi + (r1 << 8)))[j];
        const float4 vb = ((const float4*)(xi + (r2 << 8)))[j];
        const int p4 = s2i(4 * j);
        *(float4*)&w[p4]     = make_float4(va.x, vb.x, va.y, vb.y);
        *(float4*)&w[p4 + 2] = make_float4(va.z, vb.z, va.w, vb.w);
        __builtin_amdgcn_wave_barrier();
        float2 o0, o1, o2, o3;
        fft256<-1>(w, j, o0, o1, o2, o3);
        // A[k] = (Z[k]+conj(Z[256-k]))/2 (row r1); B[k] = -i(Z[k]-conj)/2 (r2)
        const int src = (64 - j) & 63;
        float2 P3, P2;
        P3.x = __shfl(o3.x, src); P3.y = __shfl(o3.y, src);   // Z[256-j], j>=1
        P2.x = __shfl(o2.x, src); P2.y = __shfl(o2.y, src);   // Z[192-j], j>=1
        const float2 Cj = (j == 0) ? make_float2(o0.x, -o0.y)
                                   : make_float2(P3.x, -P3.y);   // conj(Z[256-j])
        const float2 Ck = (j == 0) ? make_float2(P3.x, -P3.y)
                                   : make_float2(P2.x, -P2.y);   // conj(Z[192-j])
        const float2 Aj = make_float2(0.5f * (o0.x + Cj.x), 0.5f * (o0.y + Cj.y));
        const float2 Bj = make_float2(0.5f * (o0.y - Cj.y), -0.5f * (o0.x - Cj.x));
        const float2 Ak = make_float2(0.5f * (o1.x + Ck.x), 0.5f * (o1.y + Ck.y));
        const float2 Bk = make_float2(0.5f * (o1.y - Ck.y), -0.5f * (o1.x - Ck.x));
        S[r1 * 129 + j]      = pack_bf(Aj.x, Aj.y);
        S[r1 * 129 + 64 + j] = pack_bf(Ak.x, Ak.y);
        S[r2 * 129 + j]      = pack_bf(Bj.x, Bj.y);
        S[r2 * 129 + 64 + j] = pack_bf(Bk.x, Bk.y);
        if (j == 0) {
            S[r1 * 129 + 128] = pack_bf(o2.x, 0.0f);   // A[128] = Re Z[128]
            S[r2 * 129 + 128] = pack_bf(o2.y, 0.0f);   // B[128] = Im Z[128]
        }
        __builtin_amdgcn_wave_barrier();
    }
    __syncthreads();
    // col phase: wave f does cols f, f+8, ...
    for (int c = f; c <= 128; c += 8) {
#pragma unroll
        for (int k = 0; k < 4; ++k)
            w[s2i(j + 64 * k)] = unpack_bf(S[(j + 64 * k) * 129 + c]);
        __builtin_amdgcn_wave_barrier();
        float2 o0, o1, o2, o3;
        fft256<-1>(w, j, o0, o1, o2, o3);
        S[(j      ) * 129 + c] = pack_bf(o0.x, o0.y);
        S[(j +  64) * 129 + c] = pack_bf(o1.x, o1.y);
        S[(j + 128) * 129 + c] = pack_bf(o2.x, o2.y);
        S[(j + 192) * 129 + c] = pack_bf(o3.x, o3.y);
        __builtin_amdgcn_wave_barrier();
    }
    __syncthreads();
    // dump S -> Xf[bo]
    uint4* dst = (uint4*)(Xf + (size_t)bo * 33024);
    const uint4* src4 = (const uint4*)S;
    for (int e = t; e < 8256; e += 512) dst[e] = src4[e];
}

// --------------------- K2: per-bin einsum (in-place) ------------------------
// Z[b,i,n] = sum_o X[b,o,n] * W[o,i,n], n flat = h*129+w. Block = 32 n (one
// 128B line). Depth-2 register prefetch of W hides HBM latency.
__global__ __launch_bounds__(256) void k_einsum(unsigned* __restrict__ Xf,
                                                const float* __restrict__ Wt) {
    __shared__ unsigned xs[512][32];            // [(b<<6)|o][nl] = 64 KB
    const int t = threadIdx.x;
    const int bid = blockIdx.x;                 // 1032 = 8 XCD x 129
    const int nid = (bid & 7) * 129 + (bid >> 3);
    const size_t n0 = (size_t)nid * 32;

#pragma unroll
    for (int k = 0; k < 16; ++k) {
        const int e = t + 256 * k;
        const int pr = e >> 3, q = e & 7;
        const uint4 v = *reinterpret_cast<const uint4*>(
            Xf + (size_t)pr * 33024 + n0 + (q << 2));
        *reinterpret_cast<uint4*>(&xs[pr][q << 2]) = v;
    }
    __syncthreads();

    const int nl = t & 31, j = t >> 5;
    float2 acc[8][8];
#pragma unroll
    for (int r = 0; r < 8; ++r)
#pragma unroll
        for (int b = 0; b < 8; ++b) acc[r][b] = make_float2(0.0f, 0.0f);

    const float* Wb = Wt + n0 + nl;
    auto wload = [&](int o, float (&buf)[8]) {
#pragma unroll
        for (int r = 0; r < 8; ++r)
            buf[r] = __builtin_nontemporal_load(
                Wb + (size_t)((o << 6) | ((r << 3) | j)) * 33024);
    };
    auto fmab = [&](int o, const float (&wc)[8]) {
        float2 xv[8];
#pragma unroll
        for (int b = 0; b < 8; ++b) xv[b] = unpack_bf(xs[(b << 6) | o][nl]);
#pragma unroll
        for (int r = 0; r < 8; ++r)
#pragma unroll
            for (int b = 0; b < 8; ++b) {
                acc[r][b].x += xv[b].x * wc[r];
                acc[r][b].y += xv[b].y * wc[r];
            }
    };

    float wA[8], wB[8];
    wload(0, wA);
    wload(1, wB);
    for (int o = 0; o < 64; o += 2) {
        float wc0[8];
#pragma unroll
        for (int r = 0; r < 8; ++r) wc0[r] = wA[r];
        wload((o + 2) & 63, wA);                // depth-2 prefetch (wraps: cheap)
        fmab(o, wc0);
        float wc1[8];
#pragma unroll
        for (int r = 0; r < 8; ++r) wc1[r] = wB[r];
        wload((o + 3) & 63, wB);
        fmab(o + 1, wc1);
    }

#pragma unroll
    for (int r = 0; r < 8; ++r) {
        const int i = (r << 3) | j;
#pragma unroll
        for (int b = 0; b < 8; ++b) {
            Xf[(size_t)((b << 6) | i) * 33024 + n0 + nl] =
                pack_bf(acc[r][b].x, acc[r][b].y);
        }
    }
}

// ------------- K3: fused col-iFFT + row-irFFT (+bias) per image -------------
__global__ __launch_bounds__(512) void k_inv2d(const unsigned* __restrict__ Xf,
                                               const float* __restrict__ bias,
                                               float* __restrict__ y) {
    extern __shared__ char smem[];
    unsigned* S = (unsigned*)smem;
    float2* w = (float2*)(smem + 132096) + ((threadIdx.x >> 6) << 8);
    const int t = threadIdx.x, f = t >> 6, j = t & 63;
    const int bo = blockIdx.x;
    const float bv = bias[bo & 63];

    // load Xf[bo] -> S
    {
        uint4* s4 = (uint4*)S;
        const uint4* g4 = (const uint4*)(Xf + (size_t)bo * 33024);
        for (int e = t; e < 8256; e += 512) s4[e] = g4[e];
    }
    __syncthreads();
    // col inverse phase
    for (int c = f; c <= 128; c += 8) {
#pragma unroll
        for (int k = 0; k < 4; ++k)
            w[s2i(j + 64 * k)] = unpack_bf(S[(j + 64 * k) * 129 + c]);
        __builtin_amdgcn_wave_barrier();
        float2 o0, o1, o2, o3;
        fft256<+1>(w, j, o0, o1, o2, o3);
        S[(j      ) * 129 + c] = pack_bf(o0.x, o0.y);
        S[(j +  64) * 129 + c] = pack_bf(o1.x, o1.y);
        S[(j + 128) * 129 + c] = pack_bf(o2.x, o2.y);
        S[(j + 192) * 129 + c] = pack_bf(o3.x, o3.y);
        __builtin_amdgcn_wave_barrier();
    }
    __syncthreads();
    // row inverse phase (paired): z = A_ext + i*B_ext, one complex iFFT,
    // y[r1] = Re, y[r2] = Im. Self-conjugate bins k=0,128 use Re(A),Re(B)
    // ONLY (projection: reference irfft discards their imag content).
    float* yo = y + (size_t)bo * 65536;
    for (int rp = f; rp < 128; rp += 8) {
        const int r1 = rp, r2 = rp + 128;
        const unsigned* Sa = S + r1 * 129;
        const unsigned* Sb = S + r2 * 129;
        const float2 A0 = unpack_bf(Sa[j]),      B0 = unpack_bf(Sb[j]);
        const float2 A1 = unpack_bf(Sa[j + 64]), B1 = unpack_bf(Sb[j + 64]);
        const int i2 = (j == 0) ? 128 : 128 - j;
        const float2 A2 = unpack_bf(Sa[i2]),     B2 = unpack_bf(Sb[i2]);
        const float2 A3 = unpack_bf(Sa[64 - j]), B3 = unpack_bf(Sb[64 - j]);
        const float2 z0 = (j == 0)
            ? make_float2(A0.x, B0.x)                                 // k=0 projected
            : make_float2(A0.x - B0.y, A0.y + B0.x);                  // direct
        const float2 z1 = make_float2(A1.x - B1.y, A1.y + B1.x);      // k=j+64 direct
        const float2 z2 = (j == 0)
            ? make_float2(A2.x, B2.x)                                 // k=128 projected
            : make_float2(A2.x + B2.y, B2.x - A2.y);                  // reflected
        const float2 z3 = make_float2(A3.x + B3.y, B3.x - A3.y);      // reflected
        w[s2i(j)]       = z0;
        w[s2i(j +  64)] = z1;
        w[s2i(j + 128)] = z2;
        w[s2i(j + 192)] = z3;
        __builtin_amdgcn_wave_barrier();
        float2 o0, o1, o2, o3;
        fft256<+1>(w, j, o0, o1, o2, o3);
        const float sc = 1.0f / 65536.0f;
        float* y1 = yo + (r1 << 8);
        float* y2 = yo + (r2 << 8);
        __builtin_nontemporal_store(o0.x * sc + bv, y1 + j);
        __builtin_nontemporal_store(o1.x * sc + bv, y1 + j + 64);
        __builtin_nontemporal_store(o2.x * sc + bv, y1 + j + 128);
        __builtin_nontemporal_store(o3.x * sc + bv, y1 + j + 192);
        __builtin_nontemporal_store(o0.y * sc + bv, y2 + j);
        __builtin_nontemporal_store(o1.y * sc + bv, y2 + j + 64);
        __builtin_nontemporal_store(o2.y * sc + bv, y2 + j + 128);
        __builtin_nontemporal_store(o3.y * sc + bv, y2 + j + 192);
        __builtin_amdgcn_wave_barrier();
    }
}

// ---------------------------------------------------------------------------
extern "C" void kernel_launch(void* const* d_in, const int* in_sizes, int n_in,
                              void* d_out, int out_size, void* d_ws,
                              size_t ws_size, hipStream_t stream) {
    (void)in_sizes; (void)n_in; (void)out_size; (void)ws_size;
    const float* x    = (const float*)d_in[0];
    const float* wfft = (const float*)d_in[1];
    const float* bias = (const float*)d_in[2];
    float* y = (float*)d_out;
    unsigned* Xf = (unsigned*)d_ws;             // 512 x 33024 uint = 67.6 MB

    hipFuncSetAttribute((const void*)k_fwd2d,
                        hipFuncAttributeMaxDynamicSharedMemorySize, SMEM_BYTES);
    hipFuncSetAttribute((const void*)k_inv2d,
                        hipFuncAttributeMaxDynamicSharedMemorySize, SMEM_BYTES);

    k_fwd2d<<<512, 512, SMEM_BYTES, stream>>>(x, Xf);
    k_einsum<<<1032, 256, 0, stream>>>(Xf, wfft);
    k_inv2d<<<512, 512, SMEM_BYTES, stream>>>(Xf, bias, y);
}

// Round 9
// 284.839 us; speedup vs baseline: 2.7744x; 1.0062x over previous
//
#include <hip/hip_runtime.h>
#include <hip/hip_bf16.h>
#include <math.h>

#define PI_F 3.14159265358979323846f

// ---------------------------------------------------------------------------
// x (8,64,256,256) f32; weight_fft (64,64,256,129) f32; bias (64) f32
// y (8,64,256,256) f32.
// Xf workspace: complex packed-bf16, [bo][n], n = h*129+w, 512 x 33024 x 4B
// (67.6 MB -> L3-resident). All arithmetic fp32; inter-pass storage bf16.
// Round-9: twiddles depend only on lane j -> hoisted to kernel entry
// (6 float2 in registers, zero steady-state sincos in K1/K3). K2 prefetch
// wrap `&63` -> min(.,63) clamp (avoids NT re-fetch of evicted early lines).
// ---------------------------------------------------------------------------

__device__ __forceinline__ unsigned pack_bf(float re, float im) {
    unsigned ur = __float_as_uint(re);
    unsigned ui = __float_as_uint(im);
    ur = (ur + 0x7fffu + ((ur >> 16) & 1u)) >> 16;     // RNE to bf16
    ui = (ui + 0x7fffu + ((ui >> 16) & 1u)) & 0xffff0000u;
    return ur | ui;
}
__device__ __forceinline__ float2 unpack_bf(unsigned p) {
    return make_float2(__uint_as_float(p << 16),
                       __uint_as_float(p & 0xffff0000u));
}

// work-tile swizzle: spreads every round's b64 access evenly over bank pairs
__device__ __forceinline__ int s2i(int p) { return p ^ (((p >> 4) & 3) << 2); }

__device__ __forceinline__ float2 cadd(float2 a, float2 b){ return make_float2(a.x+b.x, a.y+b.y); }
__device__ __forceinline__ float2 csub(float2 a, float2 b){ return make_float2(a.x-b.x, a.y-b.y); }
__device__ __forceinline__ float2 cmul(float2 a, float2 b){ return make_float2(a.x*b.x-a.y*b.y, a.x*b.y+a.y*b.x); }

// twiddle pair for a quad2 round: w1 = e^{i th}, w2 = e^{i th/2},
// th = sgn*pi*jt*invh. Depends only on lane -> computed once per kernel.
template<int SGN>
__device__ __forceinline__ void mk_tw(int jt, float invh, float2& w1, float2& w2) {
    const float th = (SGN < 0 ? -PI_F : PI_F) * (float)jt * invh;
    __sincosf(th, &w1.y, &w1.x);
    __sincosf(0.5f * th, &w2.y, &w2.x);
}

// two radix-2 stages on quad {p, p+h, p+2h, p+3h} with precomputed twiddles
template<int SGN>
__device__ __forceinline__ void quad2(float2& u0, float2& u1, float2& u2, float2& u3,
                                      float2 w1, float2 w2) {
    const float2 t1 = cmul(w1, u1), t3 = cmul(w1, u3);
    const float2 v0 = cadd(u0, t1), v1 = csub(u0, t1);
    const float2 v2 = cadd(u2, t3), v3 = csub(u2, t3);
    const float2 t2 = cmul(w2, v2);
    float2 t4 = cmul(w2, v3);
    t4 = (SGN < 0) ? make_float2(t4.y, -t4.x) : make_float2(-t4.y, t4.x);
    u0 = cadd(v0, t2); u2 = csub(v0, t2);
    u1 = cadd(v1, t4); u3 = csub(v1, t4);
}

// 256-pt FFT by one wave. Input in natural order in w (s2i-swizzled).
// tw[6] = {w1,w2} for rounds 2,3,4 (statically indexed -> registers).
// Caller must wave_barrier() between its staging writes and this call.
template<int SGN>
__device__ __forceinline__ void fft256(float2* w, int j, const float2* tw,
                                       float2& o0, float2& o1, float2& o2, float2& o3) {
    // round 1 (stages 1-2): bit-reversed reads, trivial twiddles
    const int r = (int)(__brev((unsigned)j) >> 26);           // brev6
    float2 u0 = w[s2i(r)], u1 = w[s2i(r + 128)], u2 = w[s2i(r + 64)], u3 = w[s2i(r + 192)];
    __builtin_amdgcn_wave_barrier();                          // reads before writes
    {
        const float2 v0 = cadd(u0, u1), v1 = csub(u0, u1);
        const float2 v2 = cadd(u2, u3), v3 = csub(u2, u3);
        const float2 t4 = (SGN < 0) ? make_float2(v3.y, -v3.x) : make_float2(-v3.y, v3.x);
        u0 = cadd(v0, v2); u2 = csub(v0, v2);
        u1 = cadd(v1, t4); u3 = csub(v1, t4);
    }
    const int p4 = s2i(4 * j);                                // contiguous block of 4
    *(float4*)&w[p4]     = make_float4(u0.x, u0.y, u1.x, u1.y);
    *(float4*)&w[p4 + 2] = make_float4(u2.x, u2.y, u3.x, u3.y);
    __builtin_amdgcn_wave_barrier();
    // round 2 (stages 3-4): h=4
    {
        const int p = ((j >> 2) << 4) | (j & 3);
        float2 a0 = w[s2i(p)], a1 = w[s2i(p+4)], a2 = w[s2i(p+8)], a3 = w[s2i(p+12)];
        quad2<SGN>(a0, a1, a2, a3, tw[0], tw[1]);
        w[s2i(p)] = a0; w[s2i(p+4)] = a1; w[s2i(p+8)] = a2; w[s2i(p+12)] = a3;
    }
    __builtin_amdgcn_wave_barrier();
    // round 3 (stages 5-6): h=16
    {
        const int p = ((j >> 4) << 6) | (j & 15);
        float2 a0 = w[s2i(p)], a1 = w[s2i(p+16)], a2 = w[s2i(p+32)], a3 = w[s2i(p+48)];
        quad2<SGN>(a0, a1, a2, a3, tw[2], tw[3]);
        w[s2i(p)] = a0; w[s2i(p+16)] = a1; w[s2i(p+32)] = a2; w[s2i(p+48)] = a3;
    }
    __builtin_amdgcn_wave_barrier();
    // round 4 (stages 7-8): h=64
    {
        float2 a0 = w[s2i(j)], a1 = w[s2i(j+64)], a2 = w[s2i(j+128)], a3 = w[s2i(j+192)];
        quad2<SGN>(a0, a1, a2, a3, tw[4], tw[5]);
        o0 = a0; o1 = a1; o2 = a2; o3 = a3;
    }
}

#define SMEM_BYTES (132096 + 8 * 256 * 8)   // S (33024 u32) + 8 wave tiles

// ------------------- K1: fused row-rFFT + col-FFT per image -----------------
__global__ __launch_bounds__(512) void k_fwd2d(const float* __restrict__ x,
                                               unsigned* __restrict__ Xf) {
    extern __shared__ char smem[];
    unsigned* S = (unsigned*)smem;
    float2* w = (float2*)(smem + 132096) + ((threadIdx.x >> 6) << 8);
    const int t = threadIdx.x, f = t >> 6, j = t & 63;
    const int bo = blockIdx.x;
    const float* xi = x + (size_t)bo * 65536;

    float2 tw[6];
    mk_tw<-1>(j & 3,  0.25f,       tw[0], tw[1]);
    mk_tw<-1>(j & 15, 1.0f/16.0f,  tw[2], tw[3]);
    mk_tw<-1>(j,      1.0f/64.0f,  tw[4], tw[5]);

    // row phase (paired): wave f does row pairs (rp, rp+128). Rows are real,
    // so z = row1 + i*row2, one FFT, separate via conj-partner exchange.
    for (int rp = f; rp < 128; rp += 8) {
        const int r1 = rp, r2 = rp + 128;
        const float4 va = ((const float4*)(xi + (r1 << 8)))[j];
        const float4 vb = ((const float4*)(xi + (r2 << 8)))[j];
        const int p4 = s2i(4 * j);
        *(float4*)&w[p4]     = make_float4(va.x, vb.x, va.y, vb.y);
        *(float4*)&w[p4 + 2] = make_float4(va.z, vb.z, va.w, vb.w);
        __builtin_amdgcn_wave_barrier();
        float2 o0, o1, o2, o3;
        fft256<-1>(w, j, tw, o0, o1, o2, o3);
        // A[k] = (Z[k]+conj(Z[256-k]))/2 (row r1); B[k] = -i(Z[k]-conj)/2 (r2)
        const int src = (64 - j) & 63;
        float2 P3, P2;
        P3.x = __shfl(o3.x, src); P3.y = __shfl(o3.y, src);   // Z[256-j], j>=1
        P2.x = __shfl(o2.x, src); P2.y = __shfl(o2.y, src);   // Z[192-j], j>=1
        const float2 Cj = (j == 0) ? make_float2(o0.x, -o0.y)
                                   : make_float2(P3.x, -P3.y);   // conj(Z[256-j])
        const float2 Ck = (j == 0) ? make_float2(P3.x, -P3.y)
                                   : make_float2(P2.x, -P2.y);   // conj(Z[192-j])
        const float2 Aj = make_float2(0.5f * (o0.x + Cj.x), 0.5f * (o0.y + Cj.y));
        const float2 Bj = make_float2(0.5f * (o0.y - Cj.y), -0.5f * (o0.x - Cj.x));
        const float2 Ak = make_float2(0.5f * (o1.x + Ck.x), 0.5f * (o1.y + Ck.y));
        const float2 Bk = make_float2(0.5f * (o1.y - Ck.y), -0.5f * (o1.x - Ck.x));
        S[r1 * 129 + j]      = pack_bf(Aj.x, Aj.y);
        S[r1 * 129 + 64 + j] = pack_bf(Ak.x, Ak.y);
        S[r2 * 129 + j]      = pack_bf(Bj.x, Bj.y);
        S[r2 * 129 + 64 + j] = pack_bf(Bk.x, Bk.y);
        if (j == 0) {
            S[r1 * 129 + 128] = pack_bf(o2.x, 0.0f);   // A[128] = Re Z[128]
            S[r2 * 129 + 128] = pack_bf(o2.y, 0.0f);   // B[128] = Im Z[128]
        }
        __builtin_amdgcn_wave_barrier();
    }
    __syncthreads();
    // col phase: wave f does cols f, f+8, ...
    for (int c = f; c <= 128; c += 8) {
#pragma unroll
        for (int k = 0; k < 4; ++k)
            w[s2i(j + 64 * k)] = unpack_bf(S[(j + 64 * k) * 129 + c]);
        __builtin_amdgcn_wave_barrier();
        float2 o0, o1, o2, o3;
        fft256<-1>(w, j, tw, o0, o1, o2, o3);
        S[(j      ) * 129 + c] = pack_bf(o0.x, o0.y);
        S[(j +  64) * 129 + c] = pack_bf(o1.x, o1.y);
        S[(j + 128) * 129 + c] = pack_bf(o2.x, o2.y);
        S[(j + 192) * 129 + c] = pack_bf(o3.x, o3.y);
        __builtin_amdgcn_wave_barrier();
    }
    __syncthreads();
    // dump S -> Xf[bo]
    uint4* dst = (uint4*)(Xf + (size_t)bo * 33024);
    const uint4* src4 = (const uint4*)S;
    for (int e = t; e < 8256; e += 512) dst[e] = src4[e];
}

// --------------------- K2: per-bin einsum (in-place) ------------------------
// Z[b,i,n] = sum_o X[b,o,n] * W[o,i,n], n flat = h*129+w. Block = 32 n (one
// 128B line). Depth-2 register prefetch of W hides HBM latency.
__global__ __launch_bounds__(256) void k_einsum(unsigned* __restrict__ Xf,
                                                const float* __restrict__ Wt) {
    __shared__ unsigned xs[512][32];            // [(b<<6)|o][nl] = 64 KB
    const int t = threadIdx.x;
    const int bid = blockIdx.x;                 // 1032 = 8 XCD x 129
    const int nid = (bid & 7) * 129 + (bid >> 3);
    const size_t n0 = (size_t)nid * 32;

#pragma unroll
    for (int k = 0; k < 16; ++k) {
        const int e = t + 256 * k;
        const int pr = e >> 3, q = e & 7;
        const uint4 v = *reinterpret_cast<const uint4*>(
            Xf + (size_t)pr * 33024 + n0 + (q << 2));
        *reinterpret_cast<uint4*>(&xs[pr][q << 2]) = v;
    }
    __syncthreads();

    const int nl = t & 31, j = t >> 5;
    float2 acc[8][8];
#pragma unroll
    for (int r = 0; r < 8; ++r)
#pragma unroll
        for (int b = 0; b < 8; ++b) acc[r][b] = make_float2(0.0f, 0.0f);

    const float* Wb = Wt + n0 + nl;
    auto wload = [&](int o, float (&buf)[8]) {
#pragma unroll
        for (int r = 0; r < 8; ++r)
            buf[r] = __builtin_nontemporal_load(
                Wb + (size_t)((o << 6) | ((r << 3) | j)) * 33024);
    };
    auto fmab = [&](int o, const float (&wc)[8]) {
        float2 xv[8];
#pragma unroll
        for (int b = 0; b < 8; ++b) xv[b] = unpack_bf(xs[(b << 6) | o][nl]);
#pragma unroll
        for (int r = 0; r < 8; ++r)
#pragma unroll
            for (int b = 0; b < 8; ++b) {
                acc[r][b].x += xv[b].x * wc[r];
                acc[r][b].y += xv[b].y * wc[r];
            }
    };

    float wA[8], wB[8];
    wload(0, wA);
    wload(1, wB);
    for (int o = 0; o < 64; o += 2) {
        float wc0[8];
#pragma unroll
        for (int r = 0; r < 8; ++r) wc0[r] = wA[r];
        wload(min(o + 2, 63), wA);              // clamped prefetch (tail re-read is L2-hot)
        fmab(o, wc0);
        float wc1[8];
#pragma unroll
        for (int r = 0; r < 8; ++r) wc1[r] = wB[r];
        wload(min(o + 3, 63), wB);
        fmab(o + 1, wc1);
    }

#pragma unroll
    for (int r = 0; r < 8; ++r) {
        const int i = (r << 3) | j;
#pragma unroll
        for (int b = 0; b < 8; ++b) {
            Xf[(size_t)((b << 6) | i) * 33024 + n0 + nl] =
                pack_bf(acc[r][b].x, acc[r][b].y);
        }
    }
}

// ------------- K3: fused col-iFFT + row-irFFT (+bias) per image -------------
__global__ __launch_bounds__(512) void k_inv2d(const unsigned* __restrict__ Xf,
                                               const float* __restrict__ bias,
                                               float* __restrict__ y) {
    extern __shared__ char smem[];
    unsigned* S = (unsigned*)smem;
    float2* w = (float2*)(smem + 132096) + ((threadIdx.x >> 6) << 8);
    const int t = threadIdx.x, f = t >> 6, j = t & 63;
    const int bo = blockIdx.x;
    const float bv = bias[bo & 63];

    float2 tw[6];
    mk_tw<+1>(j & 3,  0.25f,       tw[0], tw[1]);
    mk_tw<+1>(j & 15, 1.0f/16.0f,  tw[2], tw[3]);
    mk_tw<+1>(j,      1.0f/64.0f,  tw[4], tw[5]);

    // load Xf[bo] -> S
    {
        uint4* s4 = (uint4*)S;
        const uint4* g4 = (const uint4*)(Xf + (size_t)bo * 33024);
        for (int e = t; e < 8256; e += 512) s4[e] = g4[e];
    }
    __syncthreads();
    // col inverse phase
    for (int c = f; c <= 128; c += 8) {
#pragma unroll
        for (int k = 0; k < 4; ++k)
            w[s2i(j + 64 * k)] = unpack_bf(S[(j + 64 * k) * 129 + c]);
        __builtin_amdgcn_wave_barrier();
        float2 o0, o1, o2, o3;
        fft256<+1>(w, j, tw, o0, o1, o2, o3);
        S[(j      ) * 129 + c] = pack_bf(o0.x, o0.y);
        S[(j +  64) * 129 + c] = pack_bf(o1.x, o1.y);
        S[(j + 128) * 129 + c] = pack_bf(o2.x, o2.y);
        S[(j + 192) * 129 + c] = pack_bf(o3.x, o3.y);
        __builtin_amdgcn_wave_barrier();
    }
    __syncthreads();
    // row inverse phase (paired): z = A_ext + i*B_ext, one complex iFFT,
    // y[r1] = Re, y[r2] = Im. Self-conjugate bins k=0,128 use Re(A),Re(B)
    // ONLY (projection: reference irfft discards their imag content).
    float* yo = y + (size_t)bo * 65536;
    for (int rp = f; rp < 128; rp += 8) {
        const int r1 = rp, r2 = rp + 128;
        const unsigned* Sa = S + r1 * 129;
        const unsigned* Sb = S + r2 * 129;
        const float2 A0 = unpack_bf(Sa[j]),      B0 = unpack_bf(Sb[j]);
        const float2 A1 = unpack_bf(Sa[j + 64]), B1 = unpack_bf(Sb[j + 64]);
        const int i2 = (j == 0) ? 128 : 128 - j;
        const float2 A2 = unpack_bf(Sa[i2]),     B2 = unpack_bf(Sb[i2]);
        const float2 A3 = unpack_bf(Sa[64 - j]), B3 = unpack_bf(Sb[64 - j]);
        const float2 z0 = (j == 0)
            ? make_float2(A0.x, B0.x)                                 // k=0 projected
            : make_float2(A0.x - B0.y, A0.y + B0.x);                  // direct
        const float2 z1 = make_float2(A1.x - B1.y, A1.y + B1.x);      // k=j+64 direct
        const float2 z2 = (j == 0)
            ? make_float2(A2.x, B2.x)                                 // k=128 projected
            : make_float2(A2.x + B2.y, B2.x - A2.y);                  // reflected
        const float2 z3 = make_float2(A3.x + B3.y, B3.x - A3.y);      // reflected
        w[s2i(j)]       = z0;
        w[s2i(j +  64)] = z1;
        w[s2i(j + 128)] = z2;
        w[s2i(j + 192)] = z3;
        __builtin_amdgcn_wave_barrier();
        float2 o0, o1, o2, o3;
        fft256<+1>(w, j, tw, o0, o1, o2, o3);
        const float sc = 1.0f / 65536.0f;
        float* y1 = yo + (r1 << 8);
        float* y2 = yo + (r2 << 8);
        __builtin_nontemporal_store(o0.x * sc + bv, y1 + j);
        __builtin_nontemporal_store(o1.x * sc + bv, y1 + j + 64);
        __builtin_nontemporal_store(o2.x * sc + bv, y1 + j + 128);
        __builtin_nontemporal_store(o3.x * sc + bv, y1 + j + 192);
        __builtin_nontemporal_store(o0.y * sc + bv, y2 + j);
        __builtin_nontemporal_store(o1.y * sc + bv, y2 + j + 64);
        __builtin_nontemporal_store(o2.y * sc + bv, y2 + j + 128);
        __builtin_nontemporal_store(o3.y * sc + bv, y2 + j + 192);
        __builtin_amdgcn_wave_barrier();
    }
}

// ---------------------------------------------------------------------------
extern "C" void kernel_launch(void* const* d_in, const int* in_sizes, int n_in,
                              void* d_out, int out_size, void* d_ws,
                              size_t ws_size, hipStream_t stream) {
    (void)in_sizes; (void)n_in; (void)out_size; (void)ws_size;
    const float* x    = (const float*)d_in[0];
    const float* wfft = (const float*)d_in[1];
    const float* bias = (const float*)d_in[2];
    float* y = (float*)d_out;
    unsigned* Xf = (unsigned*)d_ws;             // 512 x 33024 uint = 67.6 MB

    hipFuncSetAttribute((const void*)k_fwd2d,
                        hipFuncAttributeMaxDynamicSharedMemorySize, SMEM_BYTES);
    hipFuncSetAttribute((const void*)k_inv2d,
                        hipFuncAttributeMaxDynamicSharedMemorySize, SMEM_BYTES);

    k_fwd2d<<<512, 512, SMEM_BYTES, stream>>>(x, Xf);
    k_einsum<<<1032, 256, 0, stream>>>(Xf, wfft);
    k_inv2d<<<512, 512, SMEM_BYTES, stream>>>(Xf, bias, y);
}

// Round 10
// 284.734 us; speedup vs baseline: 2.7755x; 1.0004x over previous
//
#include <hip/hip_runtime.h>
#include <hip/hip_bf16.h>
#include <math.h>

#define PI_F 3.14159265358979323846f

// ---------------------------------------------------------------------------
// x (8,64,256,256) f32; weight_fft (64,64,256,129) f32; bias (64) f32
// y (8,64,256,256) f32.
// Xf workspace: complex packed-bf16, [bo][n], n = h*129+w, 512 x 33024 x 4B
// (67.6 MB -> L3-resident). All arithmetic fp32; inter-pass storage bf16.
// Round-9: twiddles depend only on lane j -> hoisted to kernel entry
// (6 float2 in registers, zero steady-state sincos in K1/K3). K2 prefetch
// wrap `&63` -> min(.,63) clamp (avoids NT re-fetch of evicted early lines).
// ---------------------------------------------------------------------------

__device__ __forceinline__ unsigned pack_bf(float re, float im) {
    unsigned ur = __float_as_uint(re);
    unsigned ui = __float_as_uint(im);
    ur = (ur + 0x7fffu + ((ur >> 16) & 1u)) >> 16;     // RNE to bf16
    ui = (ui + 0x7fffu + ((ui >> 16) & 1u)) & 0xffff0000u;
    return ur | ui;
}
__device__ __forceinline__ float2 unpack_bf(unsigned p) {
    return make_float2(__uint_as_float(p << 16),
                       __uint_as_float(p & 0xffff0000u));
}

// work-tile swizzle: spreads every round's b64 access evenly over bank pairs
__device__ __forceinline__ int s2i(int p) { return p ^ (((p >> 4) & 3) << 2); }

__device__ __forceinline__ float2 cadd(float2 a, float2 b){ return make_float2(a.x+b.x, a.y+b.y); }
__device__ __forceinline__ float2 csub(float2 a, float2 b){ return make_float2(a.x-b.x, a.y-b.y); }
__device__ __forceinline__ float2 cmul(float2 a, float2 b){ return make_float2(a.x*b.x-a.y*b.y, a.x*b.y+a.y*b.x); }

// twiddle pair for a quad2 round: w1 = e^{i th}, w2 = e^{i th/2},
// th = sgn*pi*jt*invh. Depends only on lane -> computed once per kernel.
template<int SGN>
__device__ __forceinline__ void mk_tw(int jt, float invh, float2& w1, float2& w2) {
    const float th = (SGN < 0 ? -PI_F : PI_F) * (float)jt * invh;
    __sincosf(th, &w1.y, &w1.x);
    __sincosf(0.5f * th, &w2.y, &w2.x);
}

// two radix-2 stages on quad {p, p+h, p+2h, p+3h} with precomputed twiddles
template<int SGN>
__device__ __forceinline__ void quad2(float2& u0, float2& u1, float2& u2, float2& u3,
                                      float2 w1, float2 w2) {
    const float2 t1 = cmul(w1, u1), t3 = cmul(w1, u3);
    const float2 v0 = cadd(u0, t1), v1 = csub(u0, t1);
    const float2 v2 = cadd(u2, t3), v3 = csub(u2, t3);
    const float2 t2 = cmul(w2, v2);
    float2 t4 = cmul(w2, v3);
    t4 = (SGN < 0) ? make_float2(t4.y, -t4.x) : make_float2(-t4.y, t4.x);
    u0 = cadd(v0, t2); u2 = csub(v0, t2);
    u1 = cadd(v1, t4); u3 = csub(v1, t4);
}

// 256-pt FFT by one wave. Input in natural order in w (s2i-swizzled).
// tw[6] = {w1,w2} for rounds 2,3,4 (statically indexed -> registers).
// Caller must wave_barrier() between its staging writes and this call.
template<int SGN>
__device__ __forceinline__ void fft256(float2* w, int j, const float2* tw,
                                       float2& o0, float2& o1, float2& o2, float2& o3) {
    // round 1 (stages 1-2): bit-reversed reads, trivial twiddles
    const int r = (int)(__brev((unsigned)j) >> 26);           // brev6
    float2 u0 = w[s2i(r)], u1 = w[s2i(r + 128)], u2 = w[s2i(r + 64)], u3 = w[s2i(r + 192)];
    __builtin_amdgcn_wave_barrier();                          // reads before writes
    {
        const float2 v0 = cadd(u0, u1), v1 = csub(u0, u1);
        const float2 v2 = cadd(u2, u3), v3 = csub(u2, u3);
        const float2 t4 = (SGN < 0) ? make_float2(v3.y, -v3.x) : make_float2(-v3.y, v3.x);
        u0 = cadd(v0, v2); u2 = csub(v0, v2);
        u1 = cadd(v1, t4); u3 = csub(v1, t4);
    }
    const int p4 = s2i(4 * j);                                // contiguous block of 4
    *(float4*)&w[p4]     = make_float4(u0.x, u0.y, u1.x, u1.y);
    *(float4*)&w[p4 + 2] = make_float4(u2.x, u2.y, u3.x, u3.y);
    __builtin_amdgcn_wave_barrier();
    // round 2 (stages 3-4): h=4
    {
        const int p = ((j >> 2) << 4) | (j & 3);
        float2 a0 = w[s2i(p)], a1 = w[s2i(p+4)], a2 = w[s2i(p+8)], a3 = w[s2i(p+12)];
        quad2<SGN>(a0, a1, a2, a3, tw[0], tw[1]);
        w[s2i(p)] = a0; w[s2i(p+4)] = a1; w[s2i(p+8)] = a2; w[s2i(p+12)] = a3;
    }
    __builtin_amdgcn_wave_barrier();
    // round 3 (stages 5-6): h=16
    {
        const int p = ((j >> 4) << 6) | (j & 15);
        float2 a0 = w[s2i(p)], a1 = w[s2i(p+16)], a2 = w[s2i(p+32)], a3 = w[s2i(p+48)];
        quad2<SGN>(a0, a1, a2, a3, tw[2], tw[3]);
        w[s2i(p)] = a0; w[s2i(p+16)] = a1; w[s2i(p+32)] = a2; w[s2i(p+48)] = a3;
    }
    __builtin_amdgcn_wave_barrier();
    // round 4 (stages 7-8): h=64
    {
        float2 a0 = w[s2i(j)], a1 = w[s2i(j+64)], a2 = w[s2i(j+128)], a3 = w[s2i(j+192)];
        quad2<SGN>(a0, a1, a2, a3, tw[4], tw[5]);
        o0 = a0; o1 = a1; o2 = a2; o3 = a3;
    }
}

#define SMEM_BYTES (132096 + 8 * 256 * 8)   // S (33024 u32) + 8 wave tiles

// ------------------- K1: fused row-rFFT + col-FFT per image -----------------
__global__ __launch_bounds__(512) void k_fwd2d(const float* __restrict__ x,
                                               unsigned* __restrict__ Xf) {
    extern __shared__ char smem[];
    unsigned* S = (unsigned*)smem;
    float2* w = (float2*)(smem + 132096) + ((threadIdx.x >> 6) << 8);
    const int t = threadIdx.x, f = t >> 6, j = t & 63;
    const int bo = blockIdx.x;
    const float* xi = x + (size_t)bo * 65536;

    float2 tw[6];
    mk_tw<-1>(j & 3,  0.25f,       tw[0], tw[1]);
    mk_tw<-1>(j & 15, 1.0f/16.0f,  tw[2], tw[3]);
    mk_tw<-1>(j,      1.0f/64.0f,  tw[4], tw[5]);

    // row phase (paired): wave f does row pairs (rp, rp+128). Rows are real,
    // so z = row1 + i*row2, one FFT, separate via conj-partner exchange.
    for (int rp = f; rp < 128; rp += 8) {
        const int r1 = rp, r2 = rp + 128;
        const float4 va = ((const float4*)(xi + (r1 << 8)))[j];
        const float4 vb = ((const float4*)(xi + (r2 << 8)))[j];
        const int p4 = s2i(4 * j);
        *(float4*)&w[p4]     = make_float4(va.x, vb.x, va.y, vb.y);
        *(float4*)&w[p4 + 2] = make_float4(va.z, vb.z, va.w, vb.w);
        __builtin_amdgcn_wave_barrier();
        float2 o0, o1, o2, o3;
        fft256<-1>(w, j, tw, o0, o1, o2, o3);
        // A[k] = (Z[k]+conj(Z[256-k]))/2 (row r1); B[k] = -i(Z[k]-conj)/2 (r2)
        const int src = (64 - j) & 63;
        float2 P3, P2;
        P3.x = __shfl(o3.x, src); P3.y = __shfl(o3.y, src);   // Z[256-j], j>=1
        P2.x = __shfl(o2.x, src); P2.y = __shfl(o2.y, src);   // Z[192-j], j>=1
        const float2 Cj = (j == 0) ? make_float2(o0.x, -o0.y)
                                   : make_float2(P3.x, -P3.y);   // conj(Z[256-j])
        const float2 Ck = (j == 0) ? make_float2(P3.x, -P3.y)
                                   : make_float2(P2.x, -P2.y);   // conj(Z[192-j])
        const float2 Aj = make_float2(0.5f * (o0.x + Cj.x), 0.5f * (o0.y + Cj.y));
        const float2 Bj = make_float2(0.5f * (o0.y - Cj.y), -0.5f * (o0.x - Cj.x));
        const float2 Ak = make_float2(0.5f * (o1.x + Ck.x), 0.5f * (o1.y + Ck.y));
        const float2 Bk = make_float2(0.5f * (o1.y - Ck.y), -0.5f * (o1.x - Ck.x));
        S[r1 * 129 + j]      = pack_bf(Aj.x, Aj.y);
        S[r1 * 129 + 64 + j] = pack_bf(Ak.x, Ak.y);
        S[r2 * 129 + j]      = pack_bf(Bj.x, Bj.y);
        S[r2 * 129 + 64 + j] = pack_bf(Bk.x, Bk.y);
        if (j == 0) {
            S[r1 * 129 + 128] = pack_bf(o2.x, 0.0f);   // A[128] = Re Z[128]
            S[r2 * 129 + 128] = pack_bf(o2.y, 0.0f);   // B[128] = Im Z[128]
        }
        __builtin_amdgcn_wave_barrier();
    }
    __syncthreads();
    // col phase: wave f does cols f, f+8, ...
    for (int c = f; c <= 128; c += 8) {
#pragma unroll
        for (int k = 0; k < 4; ++k)
            w[s2i(j + 64 * k)] = unpack_bf(S[(j + 64 * k) * 129 + c]);
        __builtin_amdgcn_wave_barrier();
        float2 o0, o1, o2, o3;
        fft256<-1>(w, j, tw, o0, o1, o2, o3);
        S[(j      ) * 129 + c] = pack_bf(o0.x, o0.y);
        S[(j +  64) * 129 + c] = pack_bf(o1.x, o1.y);
        S[(j + 128) * 129 + c] = pack_bf(o2.x, o2.y);
        S[(j + 192) * 129 + c] = pack_bf(o3.x, o3.y);
        __builtin_amdgcn_wave_barrier();
    }
    __syncthreads();
    // dump S -> Xf[bo]
    uint4* dst = (uint4*)(Xf + (size_t)bo * 33024);
    const uint4* src4 = (const uint4*)S;
    for (int e = t; e < 8256; e += 512) dst[e] = src4[e];
}

// --------------------- K2: per-bin einsum (in-place) ------------------------
// Z[b,i,n] = sum_o X[b,o,n] * W[o,i,n], n flat = h*129+w. Block = 32 n (one
// 128B line). Depth-2 register prefetch of W hides HBM latency.
__global__ __launch_bounds__(256) void k_einsum(unsigned* __restrict__ Xf,
                                                const float* __restrict__ Wt) {
    __shared__ unsigned xs[512][32];            // [(b<<6)|o][nl] = 64 KB
    const int t = threadIdx.x;
    const int bid = blockIdx.x;                 // 1032 = 8 XCD x 129
    const int nid = (bid & 7) * 129 + (bid >> 3);
    const size_t n0 = (size_t)nid * 32;

#pragma unroll
    for (int k = 0; k < 16; ++k) {
        const int e = t + 256 * k;
        const int pr = e >> 3, q = e & 7;
        const uint4 v = *reinterpret_cast<const uint4*>(
            Xf + (size_t)pr * 33024 + n0 + (q << 2));
        *reinterpret_cast<uint4*>(&xs[pr][q << 2]) = v;
    }
    __syncthreads();

    const int nl = t & 31, j = t >> 5;
    float2 acc[8][8];
#pragma unroll
    for (int r = 0; r < 8; ++r)
#pragma unroll
        for (int b = 0; b < 8; ++b) acc[r][b] = make_float2(0.0f, 0.0f);

    const float* Wb = Wt + n0 + nl;
    auto wload = [&](int o, float (&buf)[8]) {
#pragma unroll
        for (int r = 0; r < 8; ++r)
            buf[r] = __builtin_nontemporal_load(
                Wb + (size_t)((o << 6) | ((r << 3) | j)) * 33024);
    };
    auto fmab = [&](int o, const float (&wc)[8]) {
        float2 xv[8];
#pragma unroll
        for (int b = 0; b < 8; ++b) xv[b] = unpack_bf(xs[(b << 6) | o][nl]);
#pragma unroll
        for (int r = 0; r < 8; ++r)
#pragma unroll
            for (int b = 0; b < 8; ++b) {
                acc[r][b].x += xv[b].x * wc[r];
                acc[r][b].y += xv[b].y * wc[r];
            }
    };

    float wA[8], wB[8];
    wload(0, wA);
    wload(1, wB);
    for (int o = 0; o < 64; o += 2) {
        float wc0[8];
#pragma unroll
        for (int r = 0; r < 8; ++r) wc0[r] = wA[r];
        wload(min(o + 2, 63), wA);              // clamped prefetch (tail re-read is L2-hot)
        fmab(o, wc0);
        float wc1[8];
#pragma unroll
        for (int r = 0; r < 8; ++r) wc1[r] = wB[r];
        wload(min(o + 3, 63), wB);
        fmab(o + 1, wc1);
    }

#pragma unroll
    for (int r = 0; r < 8; ++r) {
        const int i = (r << 3) | j;
#pragma unroll
        for (int b = 0; b < 8; ++b) {
            Xf[(size_t)((b << 6) | i) * 33024 + n0 + nl] =
                pack_bf(acc[r][b].x, acc[r][b].y);
        }
    }
}

// ------------- K3: fused col-iFFT + row-irFFT (+bias) per image -------------
__global__ __launch_bounds__(512) void k_inv2d(const unsigned* __restrict__ Xf,
                                               const float* __restrict__ bias,
                                               float* __restrict__ y) {
    extern __shared__ char smem[];
    unsigned* S = (unsigned*)smem;
    float2* w = (float2*)(smem + 132096) + ((threadIdx.x >> 6) << 8);
    const int t = threadIdx.x, f = t >> 6, j = t & 63;
    const int bo = blockIdx.x;
    const float bv = bias[bo & 63];

    float2 tw[6];
    mk_tw<+1>(j & 3,  0.25f,       tw[0], tw[1]);
    mk_tw<+1>(j & 15, 1.0f/16.0f,  tw[2], tw[3]);
    mk_tw<+1>(j,      1.0f/64.0f,  tw[4], tw[5]);

    // load Xf[bo] -> S
    {
        uint4* s4 = (uint4*)S;
        const uint4* g4 = (const uint4*)(Xf + (size_t)bo * 33024);
        for (int e = t; e < 8256; e += 512) s4[e] = g4[e];
    }
    __syncthreads();
    // col inverse phase
    for (int c = f; c <= 128; c += 8) {
#pragma unroll
        for (int k = 0; k < 4; ++k)
            w[s2i(j + 64 * k)] = unpack_bf(S[(j + 64 * k) * 129 + c]);
        __builtin_amdgcn_wave_barrier();
        float2 o0, o1, o2, o3;
        fft256<+1>(w, j, tw, o0, o1, o2, o3);
        S[(j      ) * 129 + c] = pack_bf(o0.x, o0.y);
        S[(j +  64) * 129 + c] = pack_bf(o1.x, o1.y);
        S[(j + 128) * 129 + c] = pack_bf(o2.x, o2.y);
        S[(j + 192) * 129 + c] = pack_bf(o3.x, o3.y);
        __builtin_amdgcn_wave_barrier();
    }
    __syncthreads();
    // row inverse phase (paired): z = A_ext + i*B_ext, one complex iFFT,
    // y[r1] = Re, y[r2] = Im. Self-conjugate bins k=0,128 use Re(A),Re(B)
    // ONLY (projection: reference irfft discards their imag content).
    float* yo = y + (size_t)bo * 65536;
    for (int rp = f; rp < 128; rp += 8) {
        const int r1 = rp, r2 = rp + 128;
        const unsigned* Sa = S + r1 * 129;
        const unsigned* Sb = S + r2 * 129;
        const float2 A0 = unpack_bf(Sa[j]),      B0 = unpack_bf(Sb[j]);
        const float2 A1 = unpack_bf(Sa[j + 64]), B1 = unpack_bf(Sb[j + 64]);
        const int i2 = (j == 0) ? 128 : 128 - j;
        const float2 A2 = unpack_bf(Sa[i2]),     B2 = unpack_bf(Sb[i2]);
        const float2 A3 = unpack_bf(Sa[64 - j]), B3 = unpack_bf(Sb[64 - j]);
        const float2 z0 = (j == 0)
            ? make_float2(A0.x, B0.x)                                 // k=0 projected
            : make_float2(A0.x - B0.y, A0.y + B0.x);                  // direct
        const float2 z1 = make_float2(A1.x - B1.y, A1.y + B1.x);      // k=j+64 direct
        const float2 z2 = (j == 0)
            ? make_float2(A2.x, B2.x)                                 // k=128 projected
            : make_float2(A2.x + B2.y, B2.x - A2.y);                  // reflected
        const float2 z3 = make_float2(A3.x + B3.y, B3.x - A3.y);      // reflected
        w[s2i(j)]       = z0;
        w[s2i(j +  64)] = z1;
        w[s2i(j + 128)] = z2;
        w[s2i(j + 192)] = z3;
        __builtin_amdgcn_wave_barrier();
        float2 o0, o1, o2, o3;
        fft256<+1>(w, j, tw, o0, o1, o2, o3);
        const float sc = 1.0f / 65536.0f;
        float* y1 = yo + (r1 << 8);
        float* y2 = yo + (r2 << 8);
        __builtin_nontemporal_store(o0.x * sc + bv, y1 + j);
        __builtin_nontemporal_store(o1.x * sc + bv, y1 + j + 64);
        __builtin_nontemporal_store(o2.x * sc + bv, y1 + j + 128);
        __builtin_nontemporal_store(o3.x * sc + bv, y1 + j + 192);
        __builtin_nontemporal_store(o0.y * sc + bv, y2 + j);
        __builtin_nontemporal_store(o1.y * sc + bv, y2 + j + 64);
        __builtin_nontemporal_store(o2.y * sc + bv, y2 + j + 128);
        __builtin_nontemporal_store(o3.y * sc + bv, y2 + j + 192);
        __builtin_amdgcn_wave_barrier();
    }
}

// ---------------------------------------------------------------------------
extern "C" void kernel_launch(void* const* d_in, const int* in_sizes, int n_in,
                              void* d_out, int out_size, void* d_ws,
                              size_t ws_size, hipStream_t stream) {
    (void)in_sizes; (void)n_in; (void)out_size; (void)ws_size;
    const float* x    = (const float*)d_in[0];
    const float* wfft = (const float*)d_in[1];
    const float* bias = (const float*)d_in[2];
    float* y = (float*)d_out;
    unsigned* Xf = (unsigned*)d_ws;             // 512 x 33024 uint = 67.6 MB

    hipFuncSetAttribute((const void*)k_fwd2d,
                        hipFuncAttributeMaxDynamicSharedMemorySize, SMEM_BYTES);
    hipFuncSetAttribute((const void*)k_inv2d,
                        hipFuncAttributeMaxDynamicSharedMemorySize, SMEM_BYTES);

    k_fwd2d<<<512, 512, SMEM_BYTES, stream>>>(x, Xf);
    k_einsum<<<1032, 256, 0, stream>>>(Xf, wfft);
    k_inv2d<<<512, 512, SMEM_BYTES, stream>>>(Xf, bias, y);
}

// Round 11
// 276.979 us; speedup vs baseline: 2.8532x; 1.0280x over previous
//
#include <hip/hip_runtime.h>
#include <hip/hip_bf16.h>
#include <math.h>

#define PI_F 3.14159265358979323846f

// ---------------------------------------------------------------------------
// x (8,64,256,256) f32; weight_fft (64,64,256,129) f32; bias (64) f32
// y (8,64,256,256) f32.
// Xf workspace: complex packed-bf16, [bo][n], n = h*129+w, 512 x 33024 x 4B
// (67.6 MB -> L3-resident). All arithmetic fp32; inter-pass storage bf16.
// Round-11: K1/K3 occupancy fix. rd9's neutral twiddle-hoist showed the FFT
// kernels are LATENCY-bound (2 waves/SIMD at 148KB LDS). Now 1024 threads
// (16 waves = 4/SIMD) with 15 FFT-active waves so LDS fits:
// 132096 (S) + 15*2048 (tiles) = 162816 <= 160 KiB. Math unchanged.
// ---------------------------------------------------------------------------

#define NWACT 15   // FFT-active waves per block (wave 15: barriers+copies only)

__device__ __forceinline__ unsigned pack_bf(float re, float im) {
    unsigned ur = __float_as_uint(re);
    unsigned ui = __float_as_uint(im);
    ur = (ur + 0x7fffu + ((ur >> 16) & 1u)) >> 16;     // RNE to bf16
    ui = (ui + 0x7fffu + ((ui >> 16) & 1u)) & 0xffff0000u;
    return ur | ui;
}
__device__ __forceinline__ float2 unpack_bf(unsigned p) {
    return make_float2(__uint_as_float(p << 16),
                       __uint_as_float(p & 0xffff0000u));
}

// work-tile swizzle: spreads every round's b64 access evenly over bank pairs
__device__ __forceinline__ int s2i(int p) { return p ^ (((p >> 4) & 3) << 2); }

__device__ __forceinline__ float2 cadd(float2 a, float2 b){ return make_float2(a.x+b.x, a.y+b.y); }
__device__ __forceinline__ float2 csub(float2 a, float2 b){ return make_float2(a.x-b.x, a.y-b.y); }
__device__ __forceinline__ float2 cmul(float2 a, float2 b){ return make_float2(a.x*b.x-a.y*b.y, a.x*b.y+a.y*b.x); }

// twiddle pair for a quad2 round: w1 = e^{i th}, w2 = e^{i th/2},
// th = sgn*pi*jt*invh. Depends only on lane -> computed once per kernel.
template<int SGN>
__device__ __forceinline__ void mk_tw(int jt, float invh, float2& w1, float2& w2) {
    const float th = (SGN < 0 ? -PI_F : PI_F) * (float)jt * invh;
    __sincosf(th, &w1.y, &w1.x);
    __sincosf(0.5f * th, &w2.y, &w2.x);
}

// two radix-2 stages on quad {p, p+h, p+2h, p+3h} with precomputed twiddles
template<int SGN>
__device__ __forceinline__ void quad2(float2& u0, float2& u1, float2& u2, float2& u3,
                                      float2 w1, float2 w2) {
    const float2 t1 = cmul(w1, u1), t3 = cmul(w1, u3);
    const float2 v0 = cadd(u0, t1), v1 = csub(u0, t1);
    const float2 v2 = cadd(u2, t3), v3 = csub(u2, t3);
    const float2 t2 = cmul(w2, v2);
    float2 t4 = cmul(w2, v3);
    t4 = (SGN < 0) ? make_float2(t4.y, -t4.x) : make_float2(-t4.y, t4.x);
    u0 = cadd(v0, t2); u2 = csub(v0, t2);
    u1 = cadd(v1, t4); u3 = csub(v1, t4);
}

// 256-pt FFT by one wave. Input in natural order in w (s2i-swizzled).
// tw[6] = {w1,w2} for rounds 2,3,4 (statically indexed -> registers).
// Caller must wave_barrier() between its staging writes and this call.
template<int SGN>
__device__ __forceinline__ void fft256(float2* w, int j, const float2* tw,
                                       float2& o0, float2& o1, float2& o2, float2& o3) {
    // round 1 (stages 1-2): bit-reversed reads, trivial twiddles
    const int r = (int)(__brev((unsigned)j) >> 26);           // brev6
    float2 u0 = w[s2i(r)], u1 = w[s2i(r + 128)], u2 = w[s2i(r + 64)], u3 = w[s2i(r + 192)];
    __builtin_amdgcn_wave_barrier();                          // reads before writes
    {
        const float2 v0 = cadd(u0, u1), v1 = csub(u0, u1);
        const float2 v2 = cadd(u2, u3), v3 = csub(u2, u3);
        const float2 t4 = (SGN < 0) ? make_float2(v3.y, -v3.x) : make_float2(-v3.y, v3.x);
        u0 = cadd(v0, v2); u2 = csub(v0, v2);
        u1 = cadd(v1, t4); u3 = csub(v1, t4);
    }
    const int p4 = s2i(4 * j);                                // contiguous block of 4
    *(float4*)&w[p4]     = make_float4(u0.x, u0.y, u1.x, u1.y);
    *(float4*)&w[p4 + 2] = make_float4(u2.x, u2.y, u3.x, u3.y);
    __builtin_amdgcn_wave_barrier();
    // round 2 (stages 3-4): h=4
    {
        const int p = ((j >> 2) << 4) | (j & 3);
        float2 a0 = w[s2i(p)], a1 = w[s2i(p+4)], a2 = w[s2i(p+8)], a3 = w[s2i(p+12)];
        quad2<SGN>(a0, a1, a2, a3, tw[0], tw[1]);
        w[s2i(p)] = a0; w[s2i(p+4)] = a1; w[s2i(p+8)] = a2; w[s2i(p+12)] = a3;
    }
    __builtin_amdgcn_wave_barrier();
    // round 3 (stages 5-6): h=16
    {
        const int p = ((j >> 4) << 6) | (j & 15);
        float2 a0 = w[s2i(p)], a1 = w[s2i(p+16)], a2 = w[s2i(p+32)], a3 = w[s2i(p+48)];
        quad2<SGN>(a0, a1, a2, a3, tw[2], tw[3]);
        w[s2i(p)] = a0; w[s2i(p+16)] = a1; w[s2i(p+32)] = a2; w[s2i(p+48)] = a3;
    }
    __builtin_amdgcn_wave_barrier();
    // round 4 (stages 7-8): h=64
    {
        float2 a0 = w[s2i(j)], a1 = w[s2i(j+64)], a2 = w[s2i(j+128)], a3 = w[s2i(j+192)];
        quad2<SGN>(a0, a1, a2, a3, tw[4], tw[5]);
        o0 = a0; o1 = a1; o2 = a2; o3 = a3;
    }
}

#define SMEM_BYTES (132096 + NWACT * 256 * 8)   // S (33024 u32) + 15 wave tiles

// ------------------- K1: fused row-rFFT + col-FFT per image -----------------
__global__ __launch_bounds__(1024) void k_fwd2d(const float* __restrict__ x,
                                                unsigned* __restrict__ Xf) {
    extern __shared__ char smem[];
    unsigned* S = (unsigned*)smem;
    float2* w = (float2*)(smem + 132096) + ((threadIdx.x >> 6) << 8);
    const int t = threadIdx.x, f = t >> 6, j = t & 63;
    const int bo = blockIdx.x;
    const float* xi = x + (size_t)bo * 65536;

    float2 tw[6];
    mk_tw<-1>(j & 3,  0.25f,       tw[0], tw[1]);
    mk_tw<-1>(j & 15, 1.0f/16.0f,  tw[2], tw[3]);
    mk_tw<-1>(j,      1.0f/64.0f,  tw[4], tw[5]);

    // row phase (paired): active wave f does row pairs rp = f, f+15, ...
    if (f < NWACT) {
        for (int rp = f; rp < 128; rp += NWACT) {
            const int r1 = rp, r2 = rp + 128;
            const float4 va = ((const float4*)(xi + (r1 << 8)))[j];
            const float4 vb = ((const float4*)(xi + (r2 << 8)))[j];
            const int p4 = s2i(4 * j);
            *(float4*)&w[p4]     = make_float4(va.x, vb.x, va.y, vb.y);
            *(float4*)&w[p4 + 2] = make_float4(va.z, vb.z, va.w, vb.w);
            __builtin_amdgcn_wave_barrier();
            float2 o0, o1, o2, o3;
            fft256<-1>(w, j, tw, o0, o1, o2, o3);
            // A[k] = (Z[k]+conj(Z[256-k]))/2 (row r1); B[k] = -i(Z[k]-conj)/2 (r2)
            const int src = (64 - j) & 63;
            float2 P3, P2;
            P3.x = __shfl(o3.x, src); P3.y = __shfl(o3.y, src);   // Z[256-j], j>=1
            P2.x = __shfl(o2.x, src); P2.y = __shfl(o2.y, src);   // Z[192-j], j>=1
            const float2 Cj = (j == 0) ? make_float2(o0.x, -o0.y)
                                       : make_float2(P3.x, -P3.y);   // conj(Z[256-j])
            const float2 Ck = (j == 0) ? make_float2(P3.x, -P3.y)
                                       : make_float2(P2.x, -P2.y);   // conj(Z[192-j])
            const float2 Aj = make_float2(0.5f * (o0.x + Cj.x), 0.5f * (o0.y + Cj.y));
            const float2 Bj = make_float2(0.5f * (o0.y - Cj.y), -0.5f * (o0.x - Cj.x));
            const float2 Ak = make_float2(0.5f * (o1.x + Ck.x), 0.5f * (o1.y + Ck.y));
            const float2 Bk = make_float2(0.5f * (o1.y - Ck.y), -0.5f * (o1.x - Ck.x));
            S[r1 * 129 + j]      = pack_bf(Aj.x, Aj.y);
            S[r1 * 129 + 64 + j] = pack_bf(Ak.x, Ak.y);
            S[r2 * 129 + j]      = pack_bf(Bj.x, Bj.y);
            S[r2 * 129 + 64 + j] = pack_bf(Bk.x, Bk.y);
            if (j == 0) {
                S[r1 * 129 + 128] = pack_bf(o2.x, 0.0f);   // A[128] = Re Z[128]
                S[r2 * 129 + 128] = pack_bf(o2.y, 0.0f);   // B[128] = Im Z[128]
            }
            __builtin_amdgcn_wave_barrier();
        }
    }
    __syncthreads();
    // col phase: active wave f does cols f, f+15, ...
    if (f < NWACT) {
        for (int c = f; c <= 128; c += NWACT) {
#pragma unroll
            for (int k = 0; k < 4; ++k)
                w[s2i(j + 64 * k)] = unpack_bf(S[(j + 64 * k) * 129 + c]);
            __builtin_amdgcn_wave_barrier();
            float2 o0, o1, o2, o3;
            fft256<-1>(w, j, tw, o0, o1, o2, o3);
            S[(j      ) * 129 + c] = pack_bf(o0.x, o0.y);
            S[(j +  64) * 129 + c] = pack_bf(o1.x, o1.y);
            S[(j + 128) * 129 + c] = pack_bf(o2.x, o2.y);
            S[(j + 192) * 129 + c] = pack_bf(o3.x, o3.y);
            __builtin_amdgcn_wave_barrier();
        }
    }
    __syncthreads();
    // dump S -> Xf[bo]
    uint4* dst = (uint4*)(Xf + (size_t)bo * 33024);
    const uint4* src4 = (const uint4*)S;
    for (int e = t; e < 8256; e += 1024) dst[e] = src4[e];
}

// --------------------- K2: per-bin einsum (in-place) ------------------------
// Z[b,i,n] = sum_o X[b,o,n] * W[o,i,n], n flat = h*129+w. Block = 32 n (one
// 128B line). Depth-2 register prefetch of W hides HBM latency.
__global__ __launch_bounds__(256) void k_einsum(unsigned* __restrict__ Xf,
                                                const float* __restrict__ Wt) {
    __shared__ unsigned xs[512][32];            // [(b<<6)|o][nl] = 64 KB
    const int t = threadIdx.x;
    const int bid = blockIdx.x;                 // 1032 = 8 XCD x 129
    const int nid = (bid & 7) * 129 + (bid >> 3);
    const size_t n0 = (size_t)nid * 32;

#pragma unroll
    for (int k = 0; k < 16; ++k) {
        const int e = t + 256 * k;
        const int pr = e >> 3, q = e & 7;
        const uint4 v = *reinterpret_cast<const uint4*>(
            Xf + (size_t)pr * 33024 + n0 + (q << 2));
        *reinterpret_cast<uint4*>(&xs[pr][q << 2]) = v;
    }
    __syncthreads();

    const int nl = t & 31, j = t >> 5;
    float2 acc[8][8];
#pragma unroll
    for (int r = 0; r < 8; ++r)
#pragma unroll
        for (int b = 0; b < 8; ++b) acc[r][b] = make_float2(0.0f, 0.0f);

    const float* Wb = Wt + n0 + nl;
    auto wload = [&](int o, float (&buf)[8]) {
#pragma unroll
        for (int r = 0; r < 8; ++r)
            buf[r] = __builtin_nontemporal_load(
                Wb + (size_t)((o << 6) | ((r << 3) | j)) * 33024);
    };
    auto fmab = [&](int o, const float (&wc)[8]) {
        float2 xv[8];
#pragma unroll
        for (int b = 0; b < 8; ++b) xv[b] = unpack_bf(xs[(b << 6) | o][nl]);
#pragma unroll
        for (int r = 0; r < 8; ++r)
#pragma unroll
            for (int b = 0; b < 8; ++b) {
                acc[r][b].x += xv[b].x * wc[r];
                acc[r][b].y += xv[b].y * wc[r];
            }
    };

    float wA[8], wB[8];
    wload(0, wA);
    wload(1, wB);
    for (int o = 0; o < 64; o += 2) {
        float wc0[8];
#pragma unroll
        for (int r = 0; r < 8; ++r) wc0[r] = wA[r];
        wload(min(o + 2, 63), wA);              // clamped prefetch (tail re-read is L2-hot)
        fmab(o, wc0);
        float wc1[8];
#pragma unroll
        for (int r = 0; r < 8; ++r) wc1[r] = wB[r];
        wload(min(o + 3, 63), wB);
        fmab(o + 1, wc1);
    }

#pragma unroll
    for (int r = 0; r < 8; ++r) {
        const int i = (r << 3) | j;
#pragma unroll
        for (int b = 0; b < 8; ++b) {
            Xf[(size_t)((b << 6) | i) * 33024 + n0 + nl] =
                pack_bf(acc[r][b].x, acc[r][b].y);
        }
    }
}

// ------------- K3: fused col-iFFT + row-irFFT (+bias) per image -------------
__global__ __launch_bounds__(1024) void k_inv2d(const unsigned* __restrict__ Xf,
                                                const float* __restrict__ bias,
                                                float* __restrict__ y) {
    extern __shared__ char smem[];
    unsigned* S = (unsigned*)smem;
    float2* w = (float2*)(smem + 132096) + ((threadIdx.x >> 6) << 8);
    const int t = threadIdx.x, f = t >> 6, j = t & 63;
    const int bo = blockIdx.x;
    const float bv = bias[bo & 63];

    float2 tw[6];
    mk_tw<+1>(j & 3,  0.25f,       tw[0], tw[1]);
    mk_tw<+1>(j & 15, 1.0f/16.0f,  tw[2], tw[3]);
    mk_tw<+1>(j,      1.0f/64.0f,  tw[4], tw[5]);

    // load Xf[bo] -> S
    {
        uint4* s4 = (uint4*)S;
        const uint4* g4 = (const uint4*)(Xf + (size_t)bo * 33024);
        for (int e = t; e < 8256; e += 1024) s4[e] = g4[e];
    }
    __syncthreads();
    // col inverse phase: active wave f does cols f, f+15, ...
    if (f < NWACT) {
        for (int c = f; c <= 128; c += NWACT) {
#pragma unroll
            for (int k = 0; k < 4; ++k)
                w[s2i(j + 64 * k)] = unpack_bf(S[(j + 64 * k) * 129 + c]);
            __builtin_amdgcn_wave_barrier();
            float2 o0, o1, o2, o3;
            fft256<+1>(w, j, tw, o0, o1, o2, o3);
            S[(j      ) * 129 + c] = pack_bf(o0.x, o0.y);
            S[(j +  64) * 129 + c] = pack_bf(o1.x, o1.y);
            S[(j + 128) * 129 + c] = pack_bf(o2.x, o2.y);
            S[(j + 192) * 129 + c] = pack_bf(o3.x, o3.y);
            __builtin_amdgcn_wave_barrier();
        }
    }
    __syncthreads();
    // row inverse phase (paired): z = A_ext + i*B_ext, one complex iFFT,
    // y[r1] = Re, y[r2] = Im. Self-conjugate bins k=0,128 use Re(A),Re(B)
    // ONLY (projection: reference irfft discards their imag content).
    float* yo = y + (size_t)bo * 65536;
    if (f < NWACT) {
        for (int rp = f; rp < 128; rp += NWACT) {
            const int r1 = rp, r2 = rp + 128;
            const unsigned* Sa = S + r1 * 129;
            const unsigned* Sb = S + r2 * 129;
            const float2 A0 = unpack_bf(Sa[j]),      B0 = unpack_bf(Sb[j]);
            const float2 A1 = unpack_bf(Sa[j + 64]), B1 = unpack_bf(Sb[j + 64]);
            const int i2 = (j == 0) ? 128 : 128 - j;
            const float2 A2 = unpack_bf(Sa[i2]),     B2 = unpack_bf(Sb[i2]);
            const float2 A3 = unpack_bf(Sa[64 - j]), B3 = unpack_bf(Sb[64 - j]);
            const float2 z0 = (j == 0)
                ? make_float2(A0.x, B0.x)                                 // k=0 projected
                : make_float2(A0.x - B0.y, A0.y + B0.x);                  // direct
            const float2 z1 = make_float2(A1.x - B1.y, A1.y + B1.x);      // k=j+64 direct
            const float2 z2 = (j == 0)
                ? make_float2(A2.x, B2.x)                                 // k=128 projected
                : make_float2(A2.x + B2.y, B2.x - A2.y);                  // reflected
            const float2 z3 = make_float2(A3.x + B3.y, B3.x - A3.y);      // reflected
            w[s2i(j)]       = z0;
            w[s2i(j +  64)] = z1;
            w[s2i(j + 128)] = z2;
            w[s2i(j + 192)] = z3;
            __builtin_amdgcn_wave_barrier();
            float2 o0, o1, o2, o3;
            fft256<+1>(w, j, tw, o0, o1, o2, o3);
            const float sc = 1.0f / 65536.0f;
            float* y1 = yo + (r1 << 8);
            float* y2 = yo + (r2 << 8);
            __builtin_nontemporal_store(o0.x * sc + bv, y1 + j);
            __builtin_nontemporal_store(o1.x * sc + bv, y1 + j + 64);
            __builtin_nontemporal_store(o2.x * sc + bv, y1 + j + 128);
            __builtin_nontemporal_store(o3.x * sc + bv, y1 + j + 192);
            __builtin_nontemporal_store(o0.y * sc + bv, y2 + j);
            __builtin_nontemporal_store(o1.y * sc + bv, y2 + j + 64);
            __builtin_nontemporal_store(o2.y * sc + bv, y2 + j + 128);
            __builtin_nontemporal_store(o3.y * sc + bv, y2 + j + 192);
            __builtin_amdgcn_wave_barrier();
        }
    }
}

// ---------------------------------------------------------------------------
extern "C" void kernel_launch(void* const* d_in, const int* in_sizes, int n_in,
                              void* d_out, int out_size, void* d_ws,
                              size_t ws_size, hipStream_t stream) {
    (void)in_sizes; (void)n_in; (void)out_size; (void)ws_size;
    const float* x    = (const float*)d_in[0];
    const float* wfft = (const float*)d_in[1];
    const float* bias = (const float*)d_in[2];
    float* y = (float*)d_out;
    unsigned* Xf = (unsigned*)d_ws;             // 512 x 33024 uint = 67.6 MB

    hipFuncSetAttribute((const void*)k_fwd2d,
                        hipFuncAttributeMaxDynamicSharedMemorySize, SMEM_BYTES);
    hipFuncSetAttribute((const void*)k_inv2d,
                        hipFuncAttributeMaxDynamicSharedMemorySize, SMEM_BYTES);

    k_fwd2d<<<512, 1024, SMEM_BYTES, stream>>>(x, Xf);
    k_einsum<<<1032, 256, 0, stream>>>(Xf, wfft);
    k_inv2d<<<512, 1024, SMEM_BYTES, stream>>>(Xf, bias, y);
}

// Round 12
// 271.347 us; speedup vs baseline: 2.9124x; 1.0208x over previous
//
#include <hip/hip_runtime.h>
#include <hip/hip_bf16.h>
#include <math.h>

#define PI_F 3.14159265358979323846f

// ---------------------------------------------------------------------------
// x (8,64,256,256) f32; weight_fft (64,64,256,129) f32; bias (64) f32
// y (8,64,256,256) f32.
// Xf workspace: complex packed-bf16, [bo][n], n = h*129+w, 512 x 33024 x 4B
// (67.6 MB -> L3-resident). All arithmetic fp32; inter-pass storage bf16.
// Round-12: K1/K3 are DS-instruction-throughput-bound (rd9 VALU cut + rd11
// occupancy doubling both ~neutral). Col phases rewritten as radix-16:
// 16 lanes/FFT, 16 complex regs/lane, ONE 16x16 transpose through the dead
// cells of S itself (XOR-diagonal swizzle -> conflict-free), 4 cols/wave.
// Per-FFT DS ~238 -> ~93 cyc. Row phases, K2 unchanged.
// ---------------------------------------------------------------------------

#define NWACT 15   // FFT-active waves in ROW phases (tiles); col phase uses 16

__device__ __forceinline__ unsigned pack_bf(float re, float im) {
    unsigned ur = __float_as_uint(re);
    unsigned ui = __float_as_uint(im);
    ur = (ur + 0x7fffu + ((ur >> 16) & 1u)) >> 16;     // RNE to bf16
    ui = (ui + 0x7fffu + ((ui >> 16) & 1u)) & 0xffff0000u;
    return ur | ui;
}
__device__ __forceinline__ float2 unpack_bf(unsigned p) {
    return make_float2(__uint_as_float(p << 16),
                       __uint_as_float(p & 0xffff0000u));
}

// work-tile swizzle (row phases): spreads b64 accesses over bank pairs
__device__ __forceinline__ int s2i(int p) { return p ^ (((p >> 4) & 3) << 2); }

__device__ __forceinline__ float2 cadd(float2 a, float2 b){ return make_float2(a.x+b.x, a.y+b.y); }
__device__ __forceinline__ float2 csub(float2 a, float2 b){ return make_float2(a.x-b.x, a.y-b.y); }
__device__ __forceinline__ float2 cmul(float2 a, float2 b){ return make_float2(a.x*b.x-a.y*b.y, a.x*b.y+a.y*b.x); }

// ------------------------- row-phase FFT machinery --------------------------
template<int SGN>
__device__ __forceinline__ void mk_tw(int jt, float invh, float2& w1, float2& w2) {
    const float th = (SGN < 0 ? -PI_F : PI_F) * (float)jt * invh;
    __sincosf(th, &w1.y, &w1.x);
    __sincosf(0.5f * th, &w2.y, &w2.x);
}

template<int SGN>
__device__ __forceinline__ void quad2(float2& u0, float2& u1, float2& u2, float2& u3,
                                      float2 w1, float2 w2) {
    const float2 t1 = cmul(w1, u1), t3 = cmul(w1, u3);
    const float2 v0 = cadd(u0, t1), v1 = csub(u0, t1);
    const float2 v2 = cadd(u2, t3), v3 = csub(u2, t3);
    const float2 t2 = cmul(w2, v2);
    float2 t4 = cmul(w2, v3);
    t4 = (SGN < 0) ? make_float2(t4.y, -t4.x) : make_float2(-t4.y, t4.x);
    u0 = cadd(v0, t2); u2 = csub(v0, t2);
    u1 = cadd(v1, t4); u3 = csub(v1, t4);
}

template<int SGN>
__device__ __forceinline__ void fft256(float2* w, int j, const float2* tw,
                                       float2& o0, float2& o1, float2& o2, float2& o3) {
    const int r = (int)(__brev((unsigned)j) >> 26);           // brev6
    float2 u0 = w[s2i(r)], u1 = w[s2i(r + 128)], u2 = w[s2i(r + 64)], u3 = w[s2i(r + 192)];
    __builtin_amdgcn_wave_barrier();
    {
        const float2 v0 = cadd(u0, u1), v1 = csub(u0, u1);
        const float2 v2 = cadd(u2, u3), v3 = csub(u2, u3);
        const float2 t4 = (SGN < 0) ? make_float2(v3.y, -v3.x) : make_float2(-v3.y, v3.x);
        u0 = cadd(v0, v2); u2 = csub(v0, v2);
        u1 = cadd(v1, t4); u3 = csub(v1, t4);
    }
    const int p4 = s2i(4 * j);
    *(float4*)&w[p4]     = make_float4(u0.x, u0.y, u1.x, u1.y);
    *(float4*)&w[p4 + 2] = make_float4(u2.x, u2.y, u3.x, u3.y);
    __builtin_amdgcn_wave_barrier();
    {
        const int p = ((j >> 2) << 4) | (j & 3);
        float2 a0 = w[s2i(p)], a1 = w[s2i(p+4)], a2 = w[s2i(p+8)], a3 = w[s2i(p+12)];
        quad2<SGN>(a0, a1, a2, a3, tw[0], tw[1]);
        w[s2i(p)] = a0; w[s2i(p+4)] = a1; w[s2i(p+8)] = a2; w[s2i(p+12)] = a3;
    }
    __builtin_amdgcn_wave_barrier();
    {
        const int p = ((j >> 4) << 6) | (j & 15);
        float2 a0 = w[s2i(p)], a1 = w[s2i(p+16)], a2 = w[s2i(p+32)], a3 = w[s2i(p+48)];
        quad2<SGN>(a0, a1, a2, a3, tw[2], tw[3]);
        w[s2i(p)] = a0; w[s2i(p+16)] = a1; w[s2i(p+32)] = a2; w[s2i(p+48)] = a3;
    }
    __builtin_amdgcn_wave_barrier();
    {
        float2 a0 = w[s2i(j)], a1 = w[s2i(j+64)], a2 = w[s2i(j+128)], a3 = w[s2i(j+192)];
        quad2<SGN>(a0, a1, a2, a3, tw[4], tw[5]);
        o0 = a0; o1 = a1; o2 = a2; o3 = a3;
    }
}

// ------------------------- col-phase radix-16 machinery ---------------------
// DFT-4: outputs in natural k order (u0<-k0, u1<-k1, u2<-k2, u3<-k3)
template<int SGN>
__device__ __forceinline__ void dft4(float2& u0, float2& u1, float2& u2, float2& u3) {
    const float2 t0 = cadd(u0, u2), t1 = csub(u0, u2);
    const float2 t2 = cadd(u1, u3), t3 = csub(u1, u3);
    const float2 t3i = (SGN < 0) ? make_float2(t3.y, -t3.x) : make_float2(-t3.y, t3.x);
    u0 = cadd(t0, t2); u1 = cadd(t1, t3i);
    u2 = csub(t0, t2); u3 = csub(t1, t3i);
}

// In-register DFT-16. Input x[n1] natural; output: reg r = 4q+p holds bin
// kappa = 4p+q (digit-swapped; compensated by callers via kOf/rOf).
template<int SGN>
__device__ __forceinline__ void dft16(float2 x[16]) {
#pragma unroll
    for (int b = 0; b < 4; ++b) dft4<SGN>(x[b], x[b+4], x[b+8], x[b+12]);
    const float sg = (SGN < 0) ? -1.0f : 1.0f;
    const float C8 = 0.9238795325112867f, S8 = 0.3826834323650898f, H = 0.7071067811865476f;
    x[5]  = cmul(x[5],  make_float2(C8,  sg*S8));   // W16^1
    x[6]  = cmul(x[6],  make_float2(H,   sg*H));    // W16^2
    x[7]  = cmul(x[7],  make_float2(S8,  sg*C8));   // W16^3
    x[9]  = cmul(x[9],  make_float2(H,   sg*H));    // W16^2
    x[10] = (SGN < 0) ? make_float2(x[10].y, -x[10].x)
                      : make_float2(-x[10].y, x[10].x);   // W16^4 = +-i
    x[11] = cmul(x[11], make_float2(-H,  sg*H));    // W16^6
    x[13] = cmul(x[13], make_float2(S8,  sg*C8));   // W16^3
    x[14] = cmul(x[14], make_float2(-H,  sg*H));    // W16^6
    x[15] = cmul(x[15], make_float2(-C8, -sg*S8));  // W16^9
#pragma unroll
    for (int k1 = 0; k1 < 4; ++k1) dft4<SGN>(x[4*k1], x[4*k1+1], x[4*k1+2], x[4*k1+3]);
}

// One 256-pt col FFT over h for column c, done by a 16-lane group (lane l).
// Transpose scratch = the column's own (dead) cells in S, XOR-diagonal cell
// mapping (16*kap + (l^kap))*129 + c -> all four DS patterns conflict-free.
template<int SGN>
__device__ __forceinline__ void colfft16(unsigned* __restrict__ S, int l, int c, bool act) {
    float2 x[16];
    if (act) {
#pragma unroll
        for (int r = 0; r < 16; ++r) x[r] = unpack_bf(S[(16*r + l)*129 + c]);
    } else {
#pragma unroll
        for (int r = 0; r < 16; ++r) x[r] = make_float2(0.0f, 0.0f);
    }
    dft16<SGN>(x);
    // outer twiddle W256^{SGN*l*kappa}, iterated product
    float2 twl;
    {
        const float th = (SGN < 0 ? -1.0f : 1.0f) * (2.0f * PI_F / 256.0f) * (float)l;
        __sincosf(th, &twl.y, &twl.x);
    }
    float2 t = twl;
#pragma unroll
    for (int kk = 1; kk < 16; ++kk) {
        const int r = 4*(kk & 3) + (kk >> 2);
        x[r] = cmul(x[r], t);
        if (kk < 15) t = cmul(t, twl);
    }
    if (act) {
#pragma unroll
        for (int kk = 0; kk < 16; ++kk) {
            const int r = 4*(kk & 3) + (kk >> 2);
            S[(16*kk + (l ^ kk))*129 + c] = pack_bf(x[r].x, x[r].y);
        }
    }
    __builtin_amdgcn_wave_barrier();
    if (act) {
#pragma unroll
        for (int n2 = 0; n2 < 16; ++n2) x[n2] = unpack_bf(S[(16*l + (n2 ^ l))*129 + c]);
    }
    dft16<SGN>(x);
    if (act) {
#pragma unroll
        for (int r = 0; r < 16; ++r) {
            const int kk = 4*(r & 3) + (r >> 2);   // final k = 16*kk + l
            S[(16*kk + l)*129 + c] = pack_bf(x[r].x, x[r].y);
        }
    }
    __builtin_amdgcn_wave_barrier();
}

#define SMEM_BYTES (132096 + NWACT * 256 * 8)   // S (33024 u32) + 15 row tiles

// ------------------- K1: fused row-rFFT + col-FFT per image -----------------
__global__ __launch_bounds__(1024) void k_fwd2d(const float* __restrict__ x,
                                                unsigned* __restrict__ Xf) {
    extern __shared__ char smem[];
    unsigned* S = (unsigned*)smem;
    float2* w = (float2*)(smem + 132096) + ((threadIdx.x >> 6) << 8);
    const int t = threadIdx.x, f = t >> 6, j = t & 63;
    const int bo = blockIdx.x;
    const float* xi = x + (size_t)bo * 65536;

    float2 tw[6];
    mk_tw<-1>(j & 3,  0.25f,       tw[0], tw[1]);
    mk_tw<-1>(j & 15, 1.0f/16.0f,  tw[2], tw[3]);
    mk_tw<-1>(j,      1.0f/64.0f,  tw[4], tw[5]);

    // row phase (paired, waves 0..14): z = row_r1 + i*row_r2, one FFT,
    // separate via conj-partner exchange.
    if (f < NWACT) {
        for (int rp = f; rp < 128; rp += NWACT) {
            const int r1 = rp, r2 = rp + 128;
            const float4 va = ((const float4*)(xi + (r1 << 8)))[j];
            const float4 vb = ((const float4*)(xi + (r2 << 8)))[j];
            const int p4 = s2i(4 * j);
            *(float4*)&w[p4]     = make_float4(va.x, vb.x, va.y, vb.y);
            *(float4*)&w[p4 + 2] = make_float4(va.z, vb.z, va.w, vb.w);
            __builtin_amdgcn_wave_barrier();
            float2 o0, o1, o2, o3;
            fft256<-1>(w, j, tw, o0, o1, o2, o3);
            const int src = (64 - j) & 63;
            float2 P3, P2;
            P3.x = __shfl(o3.x, src); P3.y = __shfl(o3.y, src);   // Z[256-j]
            P2.x = __shfl(o2.x, src); P2.y = __shfl(o2.y, src);   // Z[192-j]
            const float2 Cj = (j == 0) ? make_float2(o0.x, -o0.y)
                                       : make_float2(P3.x, -P3.y);
            const float2 Ck = (j == 0) ? make_float2(P3.x, -P3.y)
                                       : make_float2(P2.x, -P2.y);
            const float2 Aj = make_float2(0.5f * (o0.x + Cj.x), 0.5f * (o0.y + Cj.y));
            const float2 Bj = make_float2(0.5f * (o0.y - Cj.y), -0.5f * (o0.x - Cj.x));
            const float2 Ak = make_float2(0.5f * (o1.x + Ck.x), 0.5f * (o1.y + Ck.y));
            const float2 Bk = make_float2(0.5f * (o1.y - Ck.y), -0.5f * (o1.x - Ck.x));
            S[r1 * 129 + j]      = pack_bf(Aj.x, Aj.y);
            S[r1 * 129 + 64 + j] = pack_bf(Ak.x, Ak.y);
            S[r2 * 129 + j]      = pack_bf(Bj.x, Bj.y);
            S[r2 * 129 + 64 + j] = pack_bf(Bk.x, Bk.y);
            if (j == 0) {
                S[r1 * 129 + 128] = pack_bf(o2.x, 0.0f);
                S[r2 * 129 + 128] = pack_bf(o2.y, 0.0f);
            }
            __builtin_amdgcn_wave_barrier();
        }
    }
    __syncthreads();
    // col phase (radix-16, all 16 waves, 4 cols/wave, cols 16 apart):
    // 33 tasks: T<16 -> {T,T+16,T+32,T+48}; 16<=T<32 -> {T+48,...}; T=32 -> 128
    {
        const int g4 = (t >> 4) & 3, l16 = t & 15;
        for (int T = f; T < 33; T += 16) {
            const int cb = (T < 16) ? T : ((T < 32) ? T + 48 : 128);
            const int c = cb + 16 * g4;
            const bool act = (T < 32) || (g4 == 0);
            colfft16<-1>(S, l16, c, act);
        }
    }
    __syncthreads();
    // dump S -> Xf[bo]
    uint4* dst = (uint4*)(Xf + (size_t)bo * 33024);
    const uint4* src4 = (const uint4*)S;
    for (int e = t; e < 8256; e += 1024) dst[e] = src4[e];
}

// --------------------- K2: per-bin einsum (in-place) ------------------------
__global__ __launch_bounds__(256) void k_einsum(unsigned* __restrict__ Xf,
                                                const float* __restrict__ Wt) {
    __shared__ unsigned xs[512][32];            // [(b<<6)|o][nl] = 64 KB
    const int t = threadIdx.x;
    const int bid = blockIdx.x;                 // 1032 = 8 XCD x 129
    const int nid = (bid & 7) * 129 + (bid >> 3);
    const size_t n0 = (size_t)nid * 32;

#pragma unroll
    for (int k = 0; k < 16; ++k) {
        const int e = t + 256 * k;
        const int pr = e >> 3, q = e & 7;
        const uint4 v = *reinterpret_cast<const uint4*>(
            Xf + (size_t)pr * 33024 + n0 + (q << 2));
        *reinterpret_cast<uint4*>(&xs[pr][q << 2]) = v;
    }
    __syncthreads();

    const int nl = t & 31, j = t >> 5;
    float2 acc[8][8];
#pragma unroll
    for (int r = 0; r < 8; ++r)
#pragma unroll
        for (int b = 0; b < 8; ++b) acc[r][b] = make_float2(0.0f, 0.0f);

    const float* Wb = Wt + n0 + nl;
    auto wload = [&](int o, float (&buf)[8]) {
#pragma unroll
        for (int r = 0; r < 8; ++r)
            buf[r] = __builtin_nontemporal_load(
                Wb + (size_t)((o << 6) | ((r << 3) | j)) * 33024);
    };
    auto fmab = [&](int o, const float (&wc)[8]) {
        float2 xv[8];
#pragma unroll
        for (int b = 0; b < 8; ++b) xv[b] = unpack_bf(xs[(b << 6) | o][nl]);
#pragma unroll
        for (int r = 0; r < 8; ++r)
#pragma unroll
            for (int b = 0; b < 8; ++b) {
                acc[r][b].x += xv[b].x * wc[r];
                acc[r][b].y += xv[b].y * wc[r];
            }
    };

    float wA[8], wB[8];
    wload(0, wA);
    wload(1, wB);
    for (int o = 0; o < 64; o += 2) {
        float wc0[8];
#pragma unroll
        for (int r = 0; r < 8; ++r) wc0[r] = wA[r];
        wload(min(o + 2, 63), wA);
        fmab(o, wc0);
        float wc1[8];
#pragma unroll
        for (int r = 0; r < 8; ++r) wc1[r] = wB[r];
        wload(min(o + 3, 63), wB);
        fmab(o + 1, wc1);
    }

#pragma unroll
    for (int r = 0; r < 8; ++r) {
        const int i = (r << 3) | j;
#pragma unroll
        for (int b = 0; b < 8; ++b) {
            Xf[(size_t)((b << 6) | i) * 33024 + n0 + nl] =
                pack_bf(acc[r][b].x, acc[r][b].y);
        }
    }
}

// ------------- K3: fused col-iFFT + row-irFFT (+bias) per image -------------
__global__ __launch_bounds__(1024) void k_inv2d(const unsigned* __restrict__ Xf,
                                                const float* __restrict__ bias,
                                                float* __restrict__ y) {
    extern __shared__ char smem[];
    unsigned* S = (unsigned*)smem;
    float2* w = (float2*)(smem + 132096) + ((threadIdx.x >> 6) << 8);
    const int t = threadIdx.x, f = t >> 6, j = t & 63;
    const int bo = blockIdx.x;
    const float bv = bias[bo & 63];

    float2 tw[6];
    mk_tw<+1>(j & 3,  0.25f,       tw[0], tw[1]);
    mk_tw<+1>(j & 15, 1.0f/16.0f,  tw[2], tw[3]);
    mk_tw<+1>(j,      1.0f/64.0f,  tw[4], tw[5]);

    // load Xf[bo] -> S
    {
        uint4* s4 = (uint4*)S;
        const uint4* g4p = (const uint4*)(Xf + (size_t)bo * 33024);
        for (int e = t; e < 8256; e += 1024) s4[e] = g4p[e];
    }
    __syncthreads();
    // col inverse phase (radix-16, all 16 waves)
    {
        const int g4 = (t >> 4) & 3, l16 = t & 15;
        for (int T = f; T < 33; T += 16) {
            const int cb = (T < 16) ? T : ((T < 32) ? T + 48 : 128);
            const int c = cb + 16 * g4;
            const bool act = (T < 32) || (g4 == 0);
            colfft16<+1>(S, l16, c, act);
        }
    }
    __syncthreads();
    // row inverse phase (paired, waves 0..14): z = A_ext + i*B_ext; k=0,128
    // projected to Re (reference irfft discards their imag content).
    float* yo = y + (size_t)bo * 65536;
    if (f < NWACT) {
        for (int rp = f; rp < 128; rp += NWACT) {
            const int r1 = rp, r2 = rp + 128;
            const unsigned* Sa = S + r1 * 129;
            const unsigned* Sb = S + r2 * 129;
            const float2 A0 = unpack_bf(Sa[j]),      B0 = unpack_bf(Sb[j]);
            const float2 A1 = unpack_bf(Sa[j + 64]), B1 = unpack_bf(Sb[j + 64]);
            const int i2 = (j == 0) ? 128 : 128 - j;
            const float2 A2 = unpack_bf(Sa[i2]),     B2 = unpack_bf(Sb[i2]);
            const float2 A3 = unpack_bf(Sa[64 - j]), B3 = unpack_bf(Sb[64 - j]);
            const float2 z0 = (j == 0)
                ? make_float2(A0.x, B0.x)
                : make_float2(A0.x - B0.y, A0.y + B0.x);
            const float2 z1 = make_float2(A1.x - B1.y, A1.y + B1.x);
            const float2 z2 = (j == 0)
                ? make_float2(A2.x, B2.x)
                : make_float2(A2.x + B2.y, B2.x - A2.y);
            const float2 z3 = make_float2(A3.x + B3.y, B3.x - A3.y);
            w[s2i(j)]       = z0;
            w[s2i(j +  64)] = z1;
            w[s2i(j + 128)] = z2;
            w[s2i(j + 192)] = z3;
            __builtin_amdgcn_wave_barrier();
            float2 o0, o1, o2, o3;
            fft256<+1>(w, j, tw, o0, o1, o2, o3);
            const float sc = 1.0f / 65536.0f;
            float* y1 = yo + (r1 << 8);
            float* y2 = yo + (r2 << 8);
            __builtin_nontemporal_store(o0.x * sc + bv, y1 + j);
            __builtin_nontemporal_store(o1.x * sc + bv, y1 + j + 64);
            __builtin_nontemporal_store(o2.x * sc + bv, y1 + j + 128);
            __builtin_nontemporal_store(o3.x * sc + bv, y1 + j + 192);
            __builtin_nontemporal_store(o0.y * sc + bv, y2 + j);
            __builtin_nontemporal_store(o1.y * sc + bv, y2 + j + 64);
            __builtin_nontemporal_store(o2.y * sc + bv, y2 + j + 128);
            __builtin_nontemporal_store(o3.y * sc + bv, y2 + j + 192);
            __builtin_amdgcn_wave_barrier();
        }
    }
}

// ---------------------------------------------------------------------------
extern "C" void kernel_launch(void* const* d_in, const int* in_sizes, int n_in,
                              void* d_out, int out_size, void* d_ws,
                              size_t ws_size, hipStream_t stream) {
    (void)in_sizes; (void)n_in; (void)out_size; (void)ws_size;
    const float* x    = (const float*)d_in[0];
    const float* wfft = (const float*)d_in[1];
    const float* bias = (const float*)d_in[2];
    float* y = (float*)d_out;
    unsigned* Xf = (unsigned*)d_ws;             // 512 x 33024 uint = 67.6 MB

    hipFuncSetAttribute((const void*)k_fwd2d,
                        hipFuncAttributeMaxDynamicSharedMemorySize, SMEM_BYTES);
    hipFuncSetAttribute((const void*)k_inv2d,
                        hipFuncAttributeMaxDynamicSharedMemorySize, SMEM_BYTES);

    k_fwd2d<<<512, 1024, SMEM_BYTES, stream>>>(x, Xf);
    k_einsum<<<1032, 256, 0, stream>>>(Xf, wfft);
    k_inv2d<<<512, 1024, SMEM_BYTES, stream>>>(Xf, bias, y);
}